// Round 11
// baseline (626.414 us; speedup 1.0000x reference)
//
#include <hip/hip_runtime.h>
#include <hip/hip_bf16.h>
#include <stdint.h>

// Problem constants
#define SEQ  4096
#define NH   16
#define HD   64

typedef __attribute__((ext_vector_type(8))) short bf16x8;
typedef __attribute__((ext_vector_type(4))) float f32x4;

__device__ __forceinline__ float bf2f(unsigned short u){
  union{unsigned u;float f;} v; v.u = ((unsigned)u)<<16; return v.f;
}
__device__ __forceinline__ unsigned short f2bf(float f){
  union{float f;unsigned u;} v; v.f=f;
  return (unsigned short)((v.u + 0x7fffu + ((v.u>>16)&1u))>>16);
}
__device__ __forceinline__ float sigm(float x){ return 1.f/(1.f+__expf(-x)); }
__device__ __forceinline__ f32x4 mfma16(bf16x8 a, bf16x8 b, f32x4 c){
  return __builtin_amdgcn_mfma_f32_16x16x32_bf16(a,b,c,0,0,0);
}
__device__ __forceinline__ void gll16(const void* g, void* l){
  __builtin_amdgcn_global_load_lds((const __attribute__((address_space(1))) void*)g,
                                   (__attribute__((address_space(3))) void*)l, 16, 0, 0);
}

// ---------------- sentinel fill ----------------
__global__ void k_fill(float* __restrict__ p, float v, long n){
  long i = (long)blockIdx.x*blockDim.x + threadIdx.x;
  long stride = (long)gridDim.x*blockDim.x;
  for (; i<n; i+=stride) p[i] = v;
}

// ---------------- f32 -> bf16 copy ----------------
__global__ void k_cvt_bf16(const float* __restrict__ in, unsigned short* __restrict__ out){
  long i = ((long)blockIdx.x*256 + threadIdx.x)*4;
  float4 v = *(const float4*)(in+i);
  ushort4 o; o.x=f2bf(v.x); o.y=f2bf(v.y); o.z=f2bf(v.z); o.w=f2bf(v.w);
  *(ushort4*)(out+i) = o;
}

// ---------------- transpose f32[R][Cin] -> bf16[Cpad][R], pad rows zeroed ----------------
__global__ void k_transpose(const float* __restrict__ in, unsigned short* __restrict__ out,
                            int R, int Cin, int Cpad){
  __shared__ float t[32][33];
  int cb = blockIdx.x*32, rb = blockIdx.y*32;
  int tx = threadIdx.x & 31, ty = threadIdx.x >> 5;
  for (int k=0;k<32;k+=8){
    int r = rb+ty+k, c = cb+tx;
    t[ty+k][tx] = (c<Cin) ? in[(long)r*Cin + c] : 0.f;
  }
  __syncthreads();
  for (int k=0;k<32;k+=8){
    int c = cb+ty+k, r = rb+tx;
    if (c<Cpad) out[(long)c*R + r] = f2bf(t[tx][ty+k]);
  }
}

#define FOR16(F) F(0,0) F(0,1) F(0,2) F(0,3) F(1,0) F(1,1) F(1,2) F(1,3) \
                 F(2,0) F(2,1) F(2,2) F(2,3) F(3,0) F(3,1) F(3,2) F(3,3)
#define FOR84(F) \
 F(0,0) F(0,1) F(0,2) F(0,3) F(1,0) F(1,1) F(1,2) F(1,3) \
 F(2,0) F(2,1) F(2,2) F(2,3) F(3,0) F(3,1) F(3,2) F(3,3) \
 F(4,0) F(4,1) F(4,2) F(4,3) F(5,0) F(5,1) F(5,2) F(5,3) \
 F(6,0) F(6,1) F(6,2) F(6,3) F(7,0) F(7,1) F(7,2) F(7,3)
#define FOR8(F) F(0) F(1) F(2) F(3) F(4) F(5) F(6) F(7)
#define ACC(i,j) Ac##i##j
#define SBAR0 __builtin_amdgcn_sched_barrier(0)

// =====================================================================
// r11: 256x256 8-wave 4-phase-per-tile GEMM with DERIVED counted waits.
// Half-tiles are K-HALVES (256x32 = 16KB = 2 gll16/thread), staged one
// per phase IN CONSUMPTION ORDER (Ak0,Bk0,Ak1,Bk1 of tile t+1 during
// tile t's phases p0..p3). Every wave's ph0 reads {Ak0,Bk0}, ph2 reads
// {Ak1,Bk1} -> at ph0/ph2 a uniform vmcnt(4) (=2 newest halves flying)
// PROVABLY covers the halves about to be read. Never drains in-loop
// (m218: counted-vs-drain0 = +38-73%). Phases: {8,4,8,4} ds_read_b128 +
// 2 gll16 + 16 MFMA between barriers. B-frags held across phase pairs.
// =====================================================================
#define MF4(A_,B0_,B1_,B2_,B3_,C0_,C1_,C2_,C3_) \
  C0_=mfma16(A_,B0_,C0_); C1_=mfma16(A_,B1_,C1_); \
  C2_=mfma16(A_,B2_,C2_); C3_=mfma16(A_,B3_,C3_);

#define GEMM256_CORE(A_,lda_,Bt_,ldb_,K_)                                      \
  __shared__ unsigned short LAs[32768];  /* 2buf x 256x64 elems = 64KB */      \
  __shared__ unsigned short LBs[32768];                                        \
  const int tid=threadIdx.x, wid=tid>>6, l=tid&63;                             \
  const int nbx=(int)gridDim.x;                                                \
  const int nwg=nbx*(int)gridDim.y;                                            \
  int flat=(int)blockIdx.y*nbx+(int)blockIdx.x;                                \
  flat=(flat&7)*(nwg>>3)+(flat>>3);                                            \
  const long m0=(long)(flat/nbx)*256, n0=(long)(flat%nbx)*256;                 \
  const int wr=wid>>2, wc=wid&3;                                               \
  const int nt=(K_)>>6;                                                        \
  char* LA=(char*)LAs; char* LB=(char*)LBs;                                    \
  const unsigned short* pA0=(A_)+(m0+(tid>>2))*(lda_)+(tid&3)*8;               \
  const unsigned short* pA1=pA0+128*(lda_);                                    \
  const unsigned short* pB0=(Bt_)+(n0+(tid>>2))*(ldb_)+(tid&3)*8;              \
  const unsigned short* pB1=pB0+128*(ldb_);                                    \
  const int dst=tid*16;                                                        \
  f32x4 Ac00={0.f,0.f,0.f,0.f};                                                \
  f32x4 Ac01=Ac00,Ac02=Ac00,Ac03=Ac00,Ac10=Ac00,Ac11=Ac00,Ac12=Ac00,Ac13=Ac00, \
        Ac20=Ac00,Ac21=Ac00,Ac22=Ac00,Ac23=Ac00,Ac30=Ac00,Ac31=Ac00,Ac32=Ac00, \
        Ac33=Ac00,Ac40=Ac00,Ac41=Ac00,Ac42=Ac00,Ac43=Ac00,Ac50=Ac00,Ac51=Ac00, \
        Ac52=Ac00,Ac53=Ac00,Ac60=Ac00,Ac61=Ac00,Ac62=Ac00,Ac63=Ac00,Ac70=Ac00, \
        Ac71=Ac00,Ac72=Ac00,Ac73=Ac00;                                         \
  /* prologue: stage tile0's 4 K-half halves in consumption order */           \
  gll16(pA0,    LA+dst); gll16(pA1,    LA+8192+dst);        /* Ak0 */          \
  gll16(pB0,    LB+dst); gll16(pB1,    LB+8192+dst);        /* Bk0 */          \
  gll16(pA0+32, LA+16384+dst); gll16(pA1+32, LA+24576+dst); /* Ak1 */          \
  gll16(pB0+32, LB+16384+dst); gll16(pB1+32, LB+24576+dst); /* Bk1 */          \
  const int aro=(wr*128+(l&15))*64+((l>>4)<<4);                                \
  const int bro=(wc*64 +(l&15))*64+((l>>4)<<4);                                \
  for (int t=0;t<nt;++t){                                                      \
    const int buf=(t&1)*32768, nb2=32768-buf;                                  \
    const long kn=((long)(t+1))<<6;                                            \
    const char* Ap0=LA+buf;       const char* Bp0=LB+buf;                      \
    const char* Ap1=Ap0+16384;    const char* Bp1=Bp0+16384;                   \
    const bool st=(t+1<nt);                                                    \
    /* ---- ph0: kh0, m0-3 x n0-3 ---- */                                      \
    asm volatile("s_waitcnt vmcnt(4)":::"memory");                             \
    SBAR0; __builtin_amdgcn_s_barrier(); SBAR0;                                \
    bf16x8 Fb0=*(const bf16x8*)(Bp0+bro);                                      \
    bf16x8 Fb1=*(const bf16x8*)(Bp0+bro+1024);                                 \
    bf16x8 Fb2=*(const bf16x8*)(Bp0+bro+2048);                                 \
    bf16x8 Fb3=*(const bf16x8*)(Bp0+bro+3072);                                 \
    bf16x8 Fa0=*(const bf16x8*)(Ap0+aro);                                      \
    bf16x8 Fa1=*(const bf16x8*)(Ap0+aro+1024);                                 \
    bf16x8 Fa2=*(const bf16x8*)(Ap0+aro+2048);                                 \
    bf16x8 Fa3=*(const bf16x8*)(Ap0+aro+3072);                                 \
    if (st){ gll16(pA0+kn, LA+nb2+dst); gll16(pA1+kn, LA+nb2+8192+dst); }      \
    __builtin_amdgcn_s_setprio(1);                                             \
    MF4(Fa0,Fb0,Fb1,Fb2,Fb3, Ac00,Ac01,Ac02,Ac03)                              \
    MF4(Fa1,Fb0,Fb1,Fb2,Fb3, Ac10,Ac11,Ac12,Ac13)                              \
    MF4(Fa2,Fb0,Fb1,Fb2,Fb3, Ac20,Ac21,Ac22,Ac23)                              \
    MF4(Fa3,Fb0,Fb1,Fb2,Fb3, Ac30,Ac31,Ac32,Ac33)                              \
    __builtin_amdgcn_s_setprio(0);                                             \
    __builtin_amdgcn_s_barrier();                                              \
    /* ---- ph1: kh0, m4-7 x n0-3 (B held) ---- */                             \
    Fa0=*(const bf16x8*)(Ap0+aro+4096);                                        \
    Fa1=*(const bf16x8*)(Ap0+aro+5120);                                        \
    Fa2=*(const bf16x8*)(Ap0+aro+6144);                                        \
    Fa3=*(const bf16x8*)(Ap0+aro+7168);                                        \
    if (st){ gll16(pB0+kn, LB+nb2+dst); gll16(pB1+kn, LB+nb2+8192+dst); }      \
    __builtin_amdgcn_s_setprio(1);                                             \
    MF4(Fa0,Fb0,Fb1,Fb2,Fb3, Ac40,Ac41,Ac42,Ac43)                              \
    MF4(Fa1,Fb0,Fb1,Fb2,Fb3, Ac50,Ac51,Ac52,Ac53)                              \
    MF4(Fa2,Fb0,Fb1,Fb2,Fb3, Ac60,Ac61,Ac62,Ac63)                              \
    MF4(Fa3,Fb0,Fb1,Fb2,Fb3, Ac70,Ac71,Ac72,Ac73)                              \
    __builtin_amdgcn_s_setprio(0);                                             \
    __builtin_amdgcn_s_barrier();                                              \
    /* ---- ph2: kh1, m0-3 x n0-3 ---- */                                      \
    if (st){ asm volatile("s_waitcnt vmcnt(4)":::"memory"); }                  \
    else   { asm volatile("s_waitcnt vmcnt(0)":::"memory"); }                  \
    SBAR0; __builtin_amdgcn_s_barrier(); SBAR0;                                \
    Fb0=*(const bf16x8*)(Bp1+bro);                                             \
    Fb1=*(const bf16x8*)(Bp1+bro+1024);                                        \
    Fb2=*(const bf16x8*)(Bp1+bro+2048);                                        \
    Fb3=*(const bf16x8*)(Bp1+bro+3072);                                        \
    Fa0=*(const bf16x8*)(Ap1+aro);                                             \
    Fa1=*(const bf16x8*)(Ap1+aro+1024);                                        \
    Fa2=*(const bf16x8*)(Ap1+aro+2048);                                        \
    Fa3=*(const bf16x8*)(Ap1+aro+3072);                                        \
    if (st){ gll16(pA0+kn+32, LA+nb2+16384+dst); gll16(pA1+kn+32, LA+nb2+24576+dst); } \
    __builtin_amdgcn_s_setprio(1);                                             \
    MF4(Fa0,Fb0,Fb1,Fb2,Fb3, Ac00,Ac01,Ac02,Ac03)                              \
    MF4(Fa1,Fb0,Fb1,Fb2,Fb3, Ac10,Ac11,Ac12,Ac13)                              \
    MF4(Fa2,Fb0,Fb1,Fb2,Fb3, Ac20,Ac21,Ac22,Ac23)                              \
    MF4(Fa3,Fb0,Fb1,Fb2,Fb3, Ac30,Ac31,Ac32,Ac33)                              \
    __builtin_amdgcn_s_setprio(0);                                             \
    __builtin_amdgcn_s_barrier();                                              \
    /* ---- ph3: kh1, m4-7 x n0-3 (B held) ---- */                             \
    Fa0=*(const bf16x8*)(Ap1+aro+4096);                                        \
    Fa1=*(const bf16x8*)(Ap1+aro+5120);                                        \
    Fa2=*(const bf16x8*)(Ap1+aro+6144);                                        \
    Fa3=*(const bf16x8*)(Ap1+aro+7168);                                        \
    if (st){ gll16(pB0+kn+32, LB+nb2+16384+dst); gll16(pB1+kn+32, LB+nb2+24576+dst); } \
    __builtin_amdgcn_s_setprio(1);                                             \
    MF4(Fa0,Fb0,Fb1,Fb2,Fb3, Ac40,Ac41,Ac42,Ac43)                              \
    MF4(Fa1,Fb0,Fb1,Fb2,Fb3, Ac50,Ac51,Ac52,Ac53)                              \
    MF4(Fa2,Fb0,Fb1,Fb2,Fb3, Ac60,Ac61,Ac62,Ac63)                              \
    MF4(Fa3,Fb0,Fb1,Fb2,Fb3, Ac70,Ac71,Ac72,Ac73)                              \
    __builtin_amdgcn_s_setprio(0);                                             \
    __builtin_amdgcn_s_barrier();                                              \
  }

// ---- ctrl projection (256^2 core). cols<3072 -> ctrl bf16; 3072..3087 -> g;
//      3088..3103 -> beta; 3104..4127 -> gate; 4128..4351 pad discarded ----
__global__ __launch_bounds__(512,2) void k_gemm_ctrl(
  const unsigned short* __restrict__ A, int lda,
  const unsigned short* __restrict__ Bt, int ldb,
  unsigned short* __restrict__ ctrl,
  float* __restrict__ gbuf, float* __restrict__ bbuf,
  unsigned short* __restrict__ gateb,
  const float* __restrict__ bias)
{
  GEMM256_CORE(A, lda, Bt, ldb, 1024)
#define EPI_CTRL(fm,fn) {                                                      \
  const int gn=(int)n0+wc*64+fn*16+(l&15);                                     \
  if (gn<4128){                                                                \
    const float bs=bias[gn];                                                   \
    _Pragma("unroll") for(int r=0;r<4;r++){                                    \
      const long gm=m0+wr*128+fm*16+((l>>4)<<2)+r;                             \
      float v=ACC(fm,fn)[r]+bs;                                                \
      if (gn<3072)      ctrl[gm*3072+gn]=f2bf(v);                              \
      else if (gn<3088) gbuf[gm*16+(gn-3072)]=                                 \
                          (v>=0.f)?-log1pf(__expf(-v)):(v-log1pf(__expf(v)));  \
      else if (gn<3104) bbuf[gm*16+(gn-3088)]=sigm(v);                         \
      else              gateb[gm*1024+(gn-3104)]=f2bf(sigm(v)); } } }
  FOR84(EPI_CTRL)
#undef EPI_CTRL
}

// ---- p20 qkv projection (256^2 core), fused mix + per-head l2norm ----
__global__ __launch_bounds__(512,2) void k_gemm_qkv(
  const unsigned short* __restrict__ A, int lda,
  const unsigned short* __restrict__ Bt, int ldb,
  const float* __restrict__ ramp,
  unsigned short* __restrict__ Qb, unsigned short* __restrict__ Kb,
  unsigned short* __restrict__ Vb)
{
  GEMM256_CORE(A, lda, Bt, ldb, 1024)
  const int seg = (int)((n0 + wc*64) >> 10);
  unsigned short* Ob = (seg==0)?Qb:((seg==1)?Kb:Vb);
  const int dc0=((int)n0+wc*64+ 0+(l&15))&1023; const float sr0=sigm(ramp[dc0]);
  const int dc1=((int)n0+wc*64+16+(l&15))&1023; const float sr1=sigm(ramp[dc1]);
  const int dc2=((int)n0+wc*64+32+(l&15))&1023; const float sr2=sigm(ramp[dc2]);
  const int dc3=((int)n0+wc*64+48+(l&15))&1023; const float sr3=sigm(ramp[dc3]);
#define EPI_QKV(fm) {                                                          \
  _Pragma("unroll") for(int r=0;r<4;r++){                                      \
    const long gm=m0+wr*128+fm*16+((l>>4)<<2)+r;                               \
    float v0=bf2f(Ob[gm*1024+dc0])+sr0*ACC(fm,0)[r];                           \
    float v1=bf2f(Ob[gm*1024+dc1])+sr1*ACC(fm,1)[r];                           \
    float v2=bf2f(Ob[gm*1024+dc2])+sr2*ACC(fm,2)[r];                           \
    float v3=bf2f(Ob[gm*1024+dc3])+sr3*ACC(fm,3)[r];                           \
    if (seg<2){                                                                \
      float ss=v0*v0+v1*v1+v2*v2+v3*v3;                                        \
      ss+=__shfl_xor(ss,1); ss+=__shfl_xor(ss,2);                              \
      ss+=__shfl_xor(ss,4); ss+=__shfl_xor(ss,8);                              \
      float rs=rsqrtf(ss+1e-6f); v0*=rs; v1*=rs; v2*=rs; v3*=rs; }             \
    Ob[gm*1024+dc0]=f2bf(v0); Ob[gm*1024+dc1]=f2bf(v1);                        \
    Ob[gm*1024+dc2]=f2bf(v2); Ob[gm*1024+dc3]=f2bf(v3); } }
  FOR8(EPI_QKV)
#undef EPI_QKV
}

// ======== 128x128 3-buffer core (kept for out-proj: N=1024) ========
#define ACC2(i,j) Bc##i##j
#define GEMM_CORE(A_,lda_,Bt_,ldb_,K_)                                         \
  __shared__ unsigned short Ab[3][4096];                                       \
  __shared__ unsigned short Bb[3][4096];                                       \
  const int tid=threadIdx.x, wid=tid>>6, l=tid&63;                             \
  const int nbx=(int)gridDim.x;                                                \
  const int nwg=nbx*(int)gridDim.y;                                            \
  int flat=(int)blockIdx.y*nbx+(int)blockIdx.x;                                \
  flat=(flat&7)*(nwg>>3)+(flat>>3);                                            \
  const long m0=(long)(flat/nbx)*128, n0=(long)(flat%nbx)*128;                 \
  const int nk=(K_)>>5;                                                        \
  const int wm=(wid>>1)*64, wn=(wid&1)*64;                                     \
  const int srow0 = tid>>2;                                                    \
  const int schunk = (((tid&3) ^ ((tid>>4)&3))<<3);                            \
  const unsigned short* gA0 = (A_) + (m0+srow0)*(lda_) + schunk;               \
  const unsigned short* gA1 = (A_) + (m0+64+srow0)*(lda_) + schunk;            \
  const unsigned short* gB0 = (Bt_) + (n0+srow0)*(ldb_) + schunk;              \
  const unsigned short* gB1 = (Bt_) + (n0+64+srow0)*(ldb_) + schunk;           \
  const int ldst0 = tid*16, ldst1 = 4096 + tid*16;                             \
  f32x4 Bc00={0.f,0.f,0.f,0.f};                                                \
  f32x4 Bc01=Bc00,Bc02=Bc00,Bc03=Bc00,Bc10=Bc00,Bc11=Bc00,Bc12=Bc00,           \
        Bc13=Bc00,Bc20=Bc00,Bc21=Bc00,Bc22=Bc00,Bc23=Bc00,Bc30=Bc00,           \
        Bc31=Bc00,Bc32=Bc00,Bc33=Bc00;                                         \
  gll16(gA0, (char*)&Ab[0][0]+ldst0); gll16(gA1, (char*)&Ab[0][0]+ldst1);      \
  gll16(gB0, (char*)&Bb[0][0]+ldst0); gll16(gB1, (char*)&Bb[0][0]+ldst1);      \
  gA0+=32; gA1+=32; gB0+=32; gB1+=32;                                          \
  gll16(gA0, (char*)&Ab[1][0]+ldst0); gll16(gA1, (char*)&Ab[1][0]+ldst1);      \
  gll16(gB0, (char*)&Bb[1][0]+ldst0); gll16(gB1, (char*)&Bb[1][0]+ldst1);      \
  gA0+=32; gA1+=32; gB0+=32; gB1+=32;                                          \
  int rb=0, sb=2;                                                              \
  const int sxor = ((l>>2)&3)<<4;                                              \
  const int rao0 = (wm+(l&15))*64 + (((l>>4)<<4) ^ sxor);                      \
  const int rbo0 = (wn+(l&15))*64 + (((l>>4)<<4) ^ sxor);                      \
  for (int kt=0; kt<nk; ++kt){                                                 \
    if (kt+1<nk) { asm volatile("s_waitcnt vmcnt(4)" ::: "memory"); }          \
    else         { asm volatile("s_waitcnt vmcnt(0)" ::: "memory"); }          \
    __builtin_amdgcn_sched_barrier(0);                                         \
    __builtin_amdgcn_s_barrier();                                              \
    __builtin_amdgcn_sched_barrier(0);                                         \
    if (kt+2<nk){                                                              \
      gll16(gA0, (char*)&Ab[sb][0]+ldst0); gll16(gA1, (char*)&Ab[sb][0]+ldst1);\
      gll16(gB0, (char*)&Bb[sb][0]+ldst0); gll16(gB1, (char*)&Bb[sb][0]+ldst1);\
      gA0+=32; gA1+=32; gB0+=32; gB1+=32;                                      \
    }                                                                          \
    const char* Apt=(const char*)&Ab[rb][0];                                   \
    const char* Bpt=(const char*)&Bb[rb][0];                                   \
    bf16x8 af0=*(const bf16x8*)(Apt+rao0);      bf16x8 bf0=*(const bf16x8*)(Bpt+rbo0);      \
    bf16x8 af1=*(const bf16x8*)(Apt+rao0+1024); bf16x8 bf1=*(const bf16x8*)(Bpt+rbo0+1024); \
    bf16x8 af2=*(const bf16x8*)(Apt+rao0+2048); bf16x8 bf2=*(const bf16x8*)(Bpt+rbo0+2048); \
    bf16x8 af3=*(const bf16x8*)(Apt+rao0+3072); bf16x8 bf3=*(const bf16x8*)(Bpt+rbo0+3072); \
    __builtin_amdgcn_s_setprio(1);                                             \
    Bc00=mfma16(af0,bf0,Bc00); Bc01=mfma16(af0,bf1,Bc01);                      \
    Bc02=mfma16(af0,bf2,Bc02); Bc03=mfma16(af0,bf3,Bc03);                      \
    Bc10=mfma16(af1,bf0,Bc10); Bc11=mfma16(af1,bf1,Bc11);                      \
    Bc12=mfma16(af1,bf2,Bc12); Bc13=mfma16(af1,bf3,Bc13);                      \
    Bc20=mfma16(af2,bf0,Bc20); Bc21=mfma16(af2,bf1,Bc21);                      \
    Bc22=mfma16(af2,bf2,Bc22); Bc23=mfma16(af2,bf3,Bc23);                      \
    Bc30=mfma16(af3,bf0,Bc30); Bc31=mfma16(af3,bf1,Bc31);                      \
    Bc32=mfma16(af3,bf2,Bc32); Bc33=mfma16(af3,bf3,Bc33);                      \
    __builtin_amdgcn_s_setprio(0);                                             \
    rb = (rb==2)?0:rb+1; sb = (sb==2)?0:sb+1;                                  \
  }

// ---- generic: f32 or bf16 out, +bias, *gate(pre-sigmoided bf16) — out-proj ----
__global__ __launch_bounds__(256,2) void k_gemm(
  const unsigned short* __restrict__ A, int lda,
  const unsigned short* __restrict__ Bt, int ldb,
  unsigned short* Cb, float* Cf, int ldc,
  int K, int Nvalid,
  const float* __restrict__ bias,
  const unsigned short* __restrict__ gate, int gld)
{
  GEMM_CORE(A, lda, Bt, ldb, K)
#define EPI_GEN(mi,ni) {                                                       \
  const int gn=(int)n0+wn+ni*16+(l&15);                                        \
  if (gn<Nvalid){                                                              \
    _Pragma("unroll") for(int r=0;r<4;r++){                                    \
      const long gm=m0+wm+mi*16+((l>>4)<<2)+r;                                 \
      float v=ACC2(mi,ni)[r];                                                  \
      if(bias) v+=bias[gn];                                                    \
      if(gate) v*=bf2f(gate[gm*gld+gn]);                                       \
      if(Cb) Cb[gm*ldc+gn]=f2bf(v); else Cf[gm*ldc+gn]=v; } } }
  FOR16(EPI_GEN)
#undef EPI_GEN
}

// ---------------- P20 scan (chunked) ----------------
__global__ void k_scan1(const float* __restrict__ hidden, const float* __restrict__ dlog,
                        const float* __restrict__ theta, float2* __restrict__ finals){
  int idx = blockIdx.x*256 + threadIdx.x;      // [b][chunk][ch]
  int ch = idx & 511; int chunk = (idx>>9) & 63; int b = idx>>15;
  float e = __expf(dlog[ch]); float r = __expf(-e);
  float th = theta[ch]; float ar = r*__cosf(th), ai = r*__sinf(th);
  const float2* src = (const float2*)hidden + ((long)b*SEQ + chunk*64)*512 + ch;
  float sr=0.f, si=0.f;
  for (int j=0;j<64;j++){
    float2 u = src[(long)j*512];
    float nr = sr*ar - si*ai + u.x;
    si = sr*ai + si*ar + u.y; sr = nr;
  }
  finals[idx] = make_float2(sr,si);
}
__global__ void k_scan2(const float* __restrict__ dlog, const float* __restrict__ theta,
                        const float2* __restrict__ finals, float2* __restrict__ carry, int nb){
  int idx = blockIdx.x*256+threadIdx.x; if (idx>=nb*512) return;
  int ch = idx & 511, b = idx>>9;
  float e = __expf(dlog[ch]); float r64 = __expf(-64.f*e);
  float ang = fmodf(64.f*theta[ch], 6.2831853071795864f);
  float cr = r64*__cosf(ang), ci = r64*__sinf(ang);
  float pr=0.f, pi=0.f;
  for (int c=0;c<64;c++){
    long o = ((long)b*64 + c)*512 + ch;
    carry[o] = make_float2(pr,pi);
    float2 f = finals[o];
    float nr = pr*cr - pi*ci + f.x;
    pi = pr*ci + pi*cr + f.y; pr = nr;
  }
}
__global__ void k_scan3(const float* __restrict__ hidden, const float* __restrict__ dlog,
                        const float* __restrict__ theta, const float2* __restrict__ carry,
                        unsigned short* __restrict__ p20){
  int idx = blockIdx.x*256 + threadIdx.x;
  int ch = idx & 511; int chunk = (idx>>9) & 63; int b = idx>>15;
  float e = __expf(dlog[ch]); float r = __expf(-e);
  float th = theta[ch]; float ar = r*__cosf(th), ai = r*__sinf(th);
  long toff = (long)b*SEQ + chunk*64;
  const float2* src = (const float2*)hidden + toff*512 + ch;
  unsigned short* dst = p20 + toff*1024 + 2*ch;
  float2 c0 = carry[idx];
  float sr=c0.x, si=c0.y;
  for (int j=0;j<64;j++){
    float2 u = src[(long)j*512];
    float nr = sr*ar - si*ai + u.x;
    si = sr*ai + si*ar + u.y; sr = nr;
    ushort2 o; o.x=f2bf(sr); o.y=f2bf(si);
    *(ushort2*)(dst + (long)j*1024) = o;
  }
}

// ---------------- rmsnorm(p20 bf16) -> fused[:,1024:2048] bf16 ----------------
__global__ __launch_bounds__(256) void k_rms_p20(const unsigned short* __restrict__ p20,
                        const float* __restrict__ vns, unsigned short* __restrict__ fused){
  long t = blockIdx.x;
  int d = threadIdx.x*4;
  ushort4 xu = *(const ushort4*)(p20 + t*1024 + d);
  float x0=bf2f(xu.x), x1=bf2f(xu.y), x2=bf2f(xu.z), x3=bf2f(xu.w);
  float ss = x0*x0 + x1*x1 + x2*x2 + x3*x3;
  for (int o=1;o<64;o<<=1) ss += __shfl_xor(ss, o);
  __shared__ float red[4];
  if ((threadIdx.x&63)==0) red[threadIdx.x>>6] = ss;
  __syncthreads();
  ss = red[0]+red[1]+red[2]+red[3];
  float rs = rsqrtf(ss*(1.f/1024.f) + 1e-6f);
  float4 s4 = *(const float4*)(vns + d);
  ushort4 o4;
  o4.x = f2bf(x0*rs*s4.x); o4.y = f2bf(x1*rs*s4.y);
  o4.z = f2bf(x2*rs*s4.z); o4.w = f2bf(x3*rs*s4.w);
  *(ushort4*)(fused + t*2048 + 1024 + d) = o4;
}

// ---------------- causal depthwise conv + SiLU (raw, pre-mix) ----------------
__global__ __launch_bounds__(256) void k_conv(const unsigned short* __restrict__ ctrl,
   const float* __restrict__ qw, const float* __restrict__ kw, const float* __restrict__ vw,
   unsigned short* __restrict__ Q, unsigned short* __restrict__ Kb, unsigned short* __restrict__ Vb){
  __shared__ unsigned short pan[19][256];
  int panel = blockIdx.x;            // 0..11
  int tb = blockIdx.y;
  int b = tb >> 8; int s0 = (tb & 255) * 16;
  int seg = panel >> 2; int d = (panel & 3)*256 + threadIdx.x;
  int c0 = panel*256;
  long base = (long)b*SEQ*3072;
  for (int rr=0; rr<19; rr++){
    int s = s0 - 3 + rr;
    pan[rr][threadIdx.x] = (s>=0) ? ctrl[base + (long)s*3072 + c0 + threadIdx.x] : (unsigned short)0;
  }
  __syncthreads();
  const float* cw = (seg==0)?qw:((seg==1)?kw:vw);
  float w0=cw[d*4], w1=cw[d*4+1], w2=cw[d*4+2], w3=cw[d*4+3];
  unsigned short* Ob = (seg==0)?Q:((seg==1)?Kb:Vb);
  for (int tk=0; tk<16; tk++){
    long t = (long)b*SEQ + s0 + tk;
    float x = bf2f(pan[tk][threadIdx.x])*w0 + bf2f(pan[tk+1][threadIdx.x])*w1
            + bf2f(pan[tk+2][threadIdx.x])*w2 + bf2f(pan[tk+3][threadIdx.x])*w3;
    x = x * sigm(x);  // silu
    Ob[t*1024 + d] = f2bf(x);
  }
}

// ---------------- delta rule phase 1: per head-chunk WY decomposition ----------------
__global__ __launch_bounds__(64,2) void k_phase1(
    const unsigned short* __restrict__ Kg, const unsigned short* __restrict__ Vg,
    const float* __restrict__ g, const float* __restrict__ beta,
    unsigned short* __restrict__ uvT, unsigned short* __restrict__ Wrm,
    unsigned short* __restrict__ Mc, unsigned short* __restrict__ BcT){
  __shared__ unsigned short Kc[64*64];     // swizzled rows
  __shared__ unsigned short Vc[64*64];     // linear
  __shared__ float Af[64*64];              // A (f32); first 8KB reused as K'^T bf16 after solve
  __shared__ unsigned short uTb[64*72];    // u_v^T [v][j] bf16 (stride 72)
  __shared__ unsigned short wTb[64*72];    // W^T  [kd][j] bf16
  __shared__ float Gs[64], betl[64], bgam[64], decC[64];

  int bid = blockIdx.x; int bh = bid>>6, c = bid&63;
  int blocal = bh>>4, h = bh&15;
  long t0 = (long)blocal*SEQ + c*64;
  int l = threadIdx.x;
  long cbase = (long)bid*4096;

  // cumulative log-decay (within chunk)
  float G = g[(t0+l)*16 + h];
  for (int o=1;o<64;o<<=1){ float n = __shfl_up(G,o); if (l>=o) G += n; }
  float bl = beta[(t0+l)*16+h];
  Gs[l]=G; betl[l]=bl; bgam[l]=bl*__expf(G);
  float G63 = __shfl(G,63);
  decC[l] = __expf(G63 - G);
  float GamC = __expf(G63);

  // stage K (swizzled via pre-swizzled global source) and V (linear)
  for (int it=0; it<8; it++){
    int bo = it*1024 + l*16;
    int row = bo>>7, bib = bo&127;
    int sb2 = bib ^ ((row&7)<<4);
    gll16(Kg + (t0+row)*1024 + h*64 + (sb2>>1),  (char*)Kc + bo);
    gll16(Vg + (t0+row)*1024 + h*64 + (bib>>1), (char*)Vc + bo);
  }
  __syncthreads();

  // K K^T -> A = strict_lower(beta_i * (k_i.k_j) * exp(Gi-Gj))  (f32)
  bf16x8 kf[2][4];
  {
    int rr = l&15;
    #pragma unroll
    for (int t=0;t<4;t++)
      #pragma unroll
      for (int h2=0;h2<2;h2++){
        int row = t*16 + rr;
        int byt = row*128 + ((h2*64 + (l>>4)*16) ^ ((row&7)<<4));
        kf[h2][t] = *(const bf16x8*)((const char*)Kc + byt);
      }
  }
  #pragma unroll
  for (int ti=0;ti<4;ti++){
    #pragma unroll
    for (int tj=0;tj<4;tj++){
      f32x4 a = {0.f,0.f,0.f,0.f};
      a = mfma16(kf[0][ti], kf[0][tj], a);
      a = mfma16(kf[1][ti], kf[1][tj], a);
      int j = tj*16 + (l&15);
      float Gj = Gs[j];
      #pragma unroll
      for (int r=0;r<4;r++){
        int i = ti*16 + ((l>>4)<<2) + r;
        Af[i*64+j] = (j<i) ? betl[i]*a[r]*__expf(Gs[i]-Gj) : 0.f;
      }
    }
  }
  __syncthreads();

  // forward substitution f32, lane = column, state in REGISTERS (r5: -200us).
  float ww[64];
  {
    float uu[64];
    #pragma unroll
    for (int i=0;i<64;i++){
      float ua = betl[i]*bf2f(Vc[i*64 + l]);
      float wa = bgam[i]*bf2f(*(const unsigned short*)((const char*)Kc + i*128 + ((2*l) ^ ((i&7)<<4))));
      #pragma unroll
      for (int j=0;j<i;j++){
        float av = Af[i*64+j];
        ua -= av*uu[j];
        wa -= av*ww[j];
      }
      uu[i] = ua; ww[i] = wa;
    }
    #pragma unroll
    for (int i=0;i<64;i+=4){
      short4 pu, pw;
      pu.x=(short)f2bf(uu[i]);   pu.y=(short)f2bf(uu[i+1]);
      pu.z=(short)f2bf(uu[i+2]); pu.w=(short)f2bf(uu[i+3]);
      pw.x=(short)f2bf(ww[i]);   pw.y=(short)f2bf(ww[i+1]);
      pw.z=(short)f2bf(ww[i+2]); pw.w=(short)f2bf(ww[i+3]);
      *(short4*)&uTb[l*72+i] = pu;
      *(short4*)&wTb[l*72+i] = pw;
    }
  }
  __syncthreads();

  // build K'^T[kd][j] = exp(G63-Gj)*K[j][kd] into first 8KB of Af (bf16, swizzled rows)
  unsigned short* KTp = (unsigned short*)Af;
  for (int j=0;j<64;j++){
    float kv = bf2f(*(const unsigned short*)((const char*)Kc + j*128 + ((2*l) ^ ((j&7)<<4))));
    *(unsigned short*)((char*)KTp + l*128 + ((2*j) ^ ((l&7)<<4))) = f2bf(decC[j]*kv);
  }
  __syncthreads();

  auto ldfragKT = [&](int t, int h2)->bf16x8{
    int row = t*16 + (l&15);
    int byt = row*128 + ((h2*64 + (l>>4)*16) ^ ((row&7)<<4));
    return *(const bf16x8*)((const char*)KTp + byt);
  };
  auto ldfrag72 = [&](const unsigned short* base, int nrow, int h2)->bf16x8{
    return *(const bf16x8*)(base + nrow*72 + h2*32 + ((l>>4)<<3));
  };

  // M_c = GamC*I - K'^T W   and   B_c = K'^T u_v (stored [v][kd] bf16)
  #pragma unroll
  for (int to=0; to<4; to++){
    bf16x8 a0 = ldfragKT(to,0), a1 = ldfragKT(to,1);
    #pragma unroll
    for (int tn=0; tn<4; tn++){
      f32x4 accv = {0.f,0.f,0.f,0.f};
      accv = mfma16(a0, ldfrag72(wTb, tn*16+(l&15), 0), accv);
      accv = mfma16(a1, ldfrag72(wTb, tn*16+(l&15), 1), accv);
      int col = tn*16 + (l&15);
      #pragma unroll
      for (int r=0;r<4;r++){
        int row = to*16 + ((l>>4)<<2) + r;
        Mc[cbase + row*64 + col] = f2bf(((row==col)? GamC : 0.f) - accv[r]);
      }
    }
    #pragma unroll
    for (int tv=0; tv<4; tv++){
      f32x4 accv = {0.f,0.f,0.f,0.f};
      accv = mfma16(a0, ldfrag72(uTb, tv*16+(l&15), 0), accv);
      accv = mfma16(a1, ldfrag72(uTb, tv*16+(l&15), 1), accv);
      int v = tv*16 + (l&15);
      int k0 = to*16 + ((l>>4)<<2);
      short4 p;
      p.x=(short)f2bf(accv[0]); p.y=(short)f2bf(accv[1]);
      p.z=(short)f2bf(accv[2]); p.w=(short)f2bf(accv[3]);
      *(short4*)&BcT[cbase + v*64 + k0] = p;
    }
  }

  // dump u_v^T [v][j] (cross-lane, via LDS) and W row-major [i][kd] (lane-local regs)
  #pragma unroll
  for (int rr=0; rr<64; rr++){
    uvT[cbase + rr*64 + l] = uTb[rr*72 + l];
    Wrm[cbase + rr*64 + l] = f2bf(ww[rr]);
  }
}

// ---------------- delta rule phase 2: per-head chunk-state chain (V-split x4) ----------------
__global__ __launch_bounds__(64,2) void k_phase2(
    const unsigned short* __restrict__ Mc, const unsigned short* __restrict__ BcT,
    unsigned short* __restrict__ Sst){
  __shared__ unsigned short ST[16*64];   // S^T slice [16 v][64 kd] bf16, swizzled
  const int bh = blockIdx.x>>2, vq = blockIdx.x&3;
  const int l = threadIdx.x;
  const int vloc = l&15;
  const int v = vq*16 + vloc;
  f32x4 Ac0={0.f,0.f,0.f,0.f};
  f32x4 Ac1=Ac0, Ac2=Ac0, Ac3=Ac0;
  for (int c=0;c<64;c++){
    long cbase = ((long)bh*64 + c)*4096;
#define P2ST(ti,A) { int kd0 = ti*16 + ((l>>4)<<2); short4 p;                  \
      p.x=(short)f2bf(A[0]); p.y=(short)f2bf(A[1]);                            \
      p.z=(short)f2bf(A[2]); p.w=(short)f2bf(A[3]);                            \
      *(short4*)&Sst[cbase + (long)v*64 + kd0] = p;                            \
      *(short4*)((char*)ST + vloc*128 + ((2*kd0) ^ ((vloc&7)<<4))) = p; }
    P2ST(0,Ac0) P2ST(1,Ac1) P2ST(2,Ac2) P2ST(3,Ac3)
#undef P2ST
    __syncthreads();
    const unsigned short* Mp = Mc + cbase;
    bf16x8 m0a = *(const bf16x8*)(Mp + ( 0+(l&15))*64 + (l>>4)*8);
    bf16x8 m0b = *(const bf16x8*)(Mp + ( 0+(l&15))*64 + 32 + (l>>4)*8);
    bf16x8 m1a = *(const bf16x8*)(Mp + (16+(l&15))*64 + (l>>4)*8);
    bf16x8 m1b = *(const bf16x8*)(Mp + (16+(l&15))*64 + 32 + (l>>4)*8);
    bf16x8 m2a = *(const bf16x8*)(Mp + (32+(l&15))*64 + (l>>4)*8);
    bf16x8 m2b = *(const bf16x8*)(Mp + (32+(l&15))*64 + 32 + (l>>4)*8);
    bf16x8 m3a = *(const bf16x8*)(Mp + (48+(l&15))*64 + (l>>4)*8);
    bf16x8 m3b = *(const bf16x8*)(Mp + (48+(l&15))*64 + 32 + (l>>4)*8);
#define P2LD(ti,A) { short4 bv = *(const short4*)&BcT[cbase + (long)v*64 + ti*16 + ((l>>4)<<2)]; \
      A[0]=bf2f((unsigned short)bv.x); A[1]=bf2f((unsigned short)bv.y);        \
      A[2]=bf2f((unsigned short)bv.z); A[3]=bf2f((unsigned short)bv.w); }
    P2LD(0,Ac0) P2LD(1,Ac1) P2LD(2,Ac2) P2LD(3,Ac3)
#undef P2LD
    bf16x8 sfa = *(const bf16x8*)((const char*)ST + vloc*128 + (((l>>4)*16) ^ ((vloc&7)<<4)));
    bf16x8 sfb = *(const bf16x8*)((const char*)ST + vloc*128 + ((64+(l>>4)*16) ^ ((vloc&7)<<4)));
    Ac0 = mfma16(m0a, sfa, Ac0); Ac0 = mfma16(m0b, sfb, Ac0);
    Ac1 = mfma16(m1a, sfa, Ac1); Ac1 = mfma16(m1b, sfb, Ac1);
    Ac2 = mfma16(m2a, sfa, Ac2); Ac2 = mfma16(m2b, sfb, Ac2);
    Ac3 = mfma16(m3a, sfa, Ac3); Ac3 = mfma16(m3b, sfb, Ac3);
    __syncthreads();
  }
}

// ---------------- delta rule phase 3: outputs + head rmsnorm -> fused[:,0:1024] ----------------
__global__ __launch_bounds__(64,2) void k_phase3(
  const unsigned short* __restrict__ Qg, const unsigned short* __restrict__ Kg,
  const float* __restrict__ g,
  const unsigned short* __restrict__ uvT, const unsigned short* __restrict__ Wrm,
  const unsigned short* __restrict__ Sst, const float* __restrict__ mns,
  unsigned short* __restrict__ fused){
  __shared__ unsigned short ST[64*64];
  __shared__ unsigned short QKl[64*64];
  __shared__ unsigned short uT[64*64];
  __shared__ float Gs[64];
  int bid = blockIdx.x; int bh = bid>>6, c = bid&63;
  int blocal = bh>>4, h = bh&15; long t0 = (long)blocal*SEQ + c*64;
  long cbase = (long)bid*4096;
  int l = threadIdx.x;

  float G = g[(t0+l)*16+h];
  for (int o=1;o<64;o<<=1){ float n=__shfl_up(G,o); if(l>=o) G+=n; }
  Gs[l]=G;

  // load S_0^T (bf16) into LDS (swizzled)
  #pragma unroll
  for (int it=0; it<16; it++){
    int flat = it*256 + l*4;
    int v = flat>>6, kd0 = flat&63;
    short4 s4 = *(const short4*)&Sst[cbase + flat];
    *(short4*)((char*)ST + v*128 + ((2*kd0) ^ ((v&7)<<4))) = s4;
  }
  __syncthreads();

  bf16x8 qf[2][4], kfr[2][4], sf[2][4];
  #pragma unroll
  for (int t=0;t<4;t++){
    long tr = t0 + t*16 + (l&15);
    qf[0][t]  = *(const bf16x8*)(Qg + tr*1024 + h*64 + (l>>4)*8);
    qf[1][t]  = *(const bf16x8*)(Qg + tr*1024 + h*64 + 32 + (l>>4)*8);
    kfr[0][t] = *(const bf16x8*)(Kg + tr*1024 + h*64 + (l>>4)*8);
    kfr[1][t] = *(const bf16x8*)(Kg + tr*1024 + h*64 + 32 + (l>>4)*8);
    int v = t*16 + (l&15);
    sf[0][t] = *(const bf16x8*)((const char*)ST + v*128 + (((l>>4)*16) ^ ((v&7)<<4)));
    sf[1][t] = *(const bf16x8*)((const char*)ST + v*128 + ((64+(l>>4)*16) ^ ((v&7)<<4)));
  }

  // QS = Q @ S0
  f32x4 qs[4][4];
  #pragma unroll
  for (int ti=0;ti<4;ti++)
    #pragma unroll
    for (int tj=0;tj<4;tj++){
      f32x4 a = {0.f,0.f,0.f,0.f};
      a = mfma16(qf[0][ti], sf[0][tj], a);
      a = mfma16(qf[1][ti], sf[1][tj], a);
      qs[ti][tj] = a;
    }

  // QK (masked, decayed) -> LDS
  #pragma unroll
  for (int ti=0;ti<4;ti++)
    #pragma unroll
    for (int tj=0;tj<4;tj++){
      f32x4 a = {0.f,0.f,0.f,0.f};
      a = mfma16(qf[0][ti], kfr[0][tj], a);
      a = mfma16(qf[1][ti], kfr[1][tj], a);
      int j = tj*16 + (l&15);
      float Gj = Gs[j];
      #pragma unroll
      for (int r=0;r<4;r++){
        int i = ti*16 + ((l>>4)<<2) + r;
        float v = (j<=i)? a[r]*__expf(Gs[i]-Gj) : 0.f;
        *(unsigned short*)((char*)QKl + i*128 + ((2*j) ^ ((i&7)<<4))) = f2bf(v);
      }
    }

  // WS = W @ S0 ;  u^T = u_v^T - WS^T -> LDS
  #pragma unroll
  for (int ti=0; ti<4; ti++){
    int irow = ti*16 + (l&15);
    bf16x8 w0 = *(const bf16x8*)(Wrm + cbase + irow*64 + (l>>4)*8);
    bf16x8 w1 = *(const bf16x8*)(Wrm + cbase + irow*64 + 32 + (l>>4)*8);
    #pragma unroll
    for (int tj=0; tj<4; tj++){
      f32x4 a = {0.f,0.f,0.f,0.f};
      a = mfma16(w0, sf[0][tj], a);
      a = mfma16(w1, sf[1][tj], a);
      int v = tj*16 + (l&15);
      int i0 = ti*16 + ((l>>4)<<2);
      short4 uv4 = *(const short4*)(uvT + cbase + (long)v*64 + i0);
      short4 p;
      p.x=(short)f2bf(bf2f((unsigned short)uv4.x) - a[0]);
      p.y=(short)f2bf(bf2f((unsigned short)uv4.y) - a[1]);
      p.z=(short)f2bf(bf2f((unsigned short)uv4.z) - a[2]);
      p.w=(short)f2bf(bf2f((unsigned short)uv4.w) - a[3]);
      *(short4*)((char*)uT + v*128 + ((2*i0) ^ ((v&7)<<4))) = p;
    }
  }
  __syncthreads();

  // o = Gam_i * QS + QK @ u ; then head rmsnorm; write
  float mscale[4];
  #pragma unroll
  for (int tj=0;tj<4;tj++) mscale[tj] = mns[tj*16 + (l&15)];
  #pragma unroll
  for (int ti=0; ti<4; ti++){
    int row = ti*16 + (l&15);
    bf16x8 qk0 = *(const bf16x8*)((const char*)QKl + row*128 + (((l>>4)*16) ^ ((row&7)<<4)));
    bf16x8 qk1 = *(const bf16x8*)((const char*)QKl + row*128 + ((64+(l>>4)*16) ^ ((row&7)<<4)));
    #pragma unroll
    for (int tj=0; tj<4; tj++){
      int v = tj*16 + (l&15);
      bf16x8 u0 = *(const bf16x8*)((const char*)uT + v*128 + (((l>>4)*16) ^ ((v&7)<<4)));
      bf16x8 u1 = *(const bf16x8*)((const char*)uT + v*128 + ((64+(l>>4)*16) ^ ((v&7)<<4)));
      f32x4 a;
      #pragma unroll
      for (int r=0;r<4;r++){
        float gam = __expf(Gs[ti*16 + ((l>>4)<<2) + r]);
        a[r] = qs[ti][tj][r]*gam;
      }
      a = mfma16(qk0,u0,a);
      a = mfma16(qk1,u1,a);
      qs[ti][tj] = a;
    }
  }
  #pragma unroll
  for (int ti=0; ti<4; ti++){
    #pragma unroll
    for (int r=0; r<4; r++){
      float ss = 0.f;
      #pragma unroll
      for (int tj=0;tj<4;tj++){ float v = qs[ti][tj][r]*0.125f; ss += v*v; }
      ss += __shfl_xor(ss,1); ss += __shfl_xor(ss,2); ss += __shfl_xor(ss,4); ss += __shfl_xor(ss,8);
      float rs = rsqrtf(ss*(1.f/64.f) + 1e-6f);
      long t = t0 + ti*16 + ((l>>4)<<2) + r;
      #pragma unroll
      for (int tj=0;tj<4;tj++){
        float on = qs[ti][tj][r]*0.125f*rs*mscale[tj];
        fused[t*2048 + h*64 + tj*16 + (l&15)] = f2bf(on);
      }
    }
  }
}

// =======================================================================
extern "C" void kernel_launch(void* const* d_in, const int* in_sizes, int n_in,
                              void* d_out, int out_size, void* d_ws, size_t ws_size,
                              hipStream_t stream){
  (void)in_sizes; (void)n_in;
  const float* hidden = (const float*)d_in[0];
  const float* dlog   = (const float*)d_in[1];
  const float* theta  = (const float*)d_in[2];
  const float* ctrlW  = (const float*)d_in[3];
  const float* ctrlb  = (const float*)d_in[4];
  const float* p20cW  = (const float*)d_in[5];
  const float* qw     = (const float*)d_in[6];
  const float* kw     = (const float*)d_in[7];
  const float* vw     = (const float*)d_in[8];
  const float* mns    = (const float*)d_in[9];
  const float* vns    = (const float*)d_in[10];
  const float* ramp   = (const float*)d_in[11];
  const float* outW   = (const float*)d_in[12];
  const float* outb   = (const float*)d_in[13];
  float* out = (float*)d_out;

  struct Bufs {
    unsigned short *ctrl, *uvT, *Wrm, *Mc;
    unsigned short *Qb, *Kb, *Vb, *fused;
    unsigned short *E_hid, *E_p20, *BcT;
    unsigned short *Sst, *gateb, *ctrlWT, *p20WT, *outWT;
    float2 *finals, *carry; float *gbuf, *bbuf;
    size_t need;
  };
  auto mk = [&](size_t NT)->Bufs{
    Bufs B; size_t off=0;
    auto tk=[&](size_t n)->char*{ char* p=(char*)d_ws+off; off += (n+255)&~(size_t)255; return p; };
    char* Rctrl = tk(NT*3072*2);                       // ctrl -> uvT|Wrm|Mc (byte-exact)
    B.ctrl=(unsigned short*)Rctrl;
    B.uvT=(unsigned short*)Rctrl; B.Wrm=B.uvT + NT*1024; B.Mc=B.Wrm + NT*1024;
    char* Rqkv = tk(NT*1024*2*3);
    B.Qb=(unsigned short*)Rqkv; B.Kb=B.Qb+NT*1024; B.Vb=B.Kb+NT*1024;
    B.fused=(unsigned short*)tk(NT*2048*2);
    char* RE = tk(NT*1024*2);                          // hid_bf -> p20(bf16) -> BcT
    B.E_hid=(unsigned short*)RE; B.E_p20=(unsigned short*)RE; B.BcT=(unsigned short*)RE;
    B.Sst=(unsigned short*)tk(NT*1024*2);
    B.gateb=(unsigned short*)tk(NT*1024*2);
    B.ctrlWT=(unsigned short*)tk((size_t)4352*1024*2);
    B.p20WT=(unsigned short*)tk((size_t)3072*1024*2);
    B.outWT=(unsigned short*)tk((size_t)1024*2048*2);
    B.finals=(float2*)tk(NT*64);
    B.carry=(float2*)tk(NT*64);
    B.gbuf=(float*)tk(NT*16*4);
    B.bbuf=(float*)tk(NT*16*4);
    B.need=off;
    return B;
  };

  Bufs Bf = mk(8192);
  Bufs Bh = mk(4096);
  Bufs B; size_t NT; int nb;
  if      (Bf.need <= ws_size){ B=Bf; NT=8192; nb=2; }
  else if (Bh.need <= ws_size){ B=Bh; NT=4096; nb=1; }
  else {
    k_fill<<<2048,256,0,stream>>>(out, (float)((double)ws_size), (long)out_size);
    return;
  }

  // weight prep (once; regions never overlaid)
  k_transpose<<<dim3(136,32),256,0,stream>>>(ctrlW, B.ctrlWT, 1024, 4128, 4352);
  k_transpose<<<dim3(96,32), 256,0,stream>>>(p20cW, B.p20WT, 1024, 3072, 3072);
  k_transpose<<<dim3(32,64), 256,0,stream>>>(outW,  B.outWT, 2048, 1024, 1024);

  for (int b0=0; b0<2; b0+=nb){
    const float* hidb = hidden + (size_t)b0*SEQ*1024;
    float* outp = out + (size_t)b0*SEQ*1024;
    // hidden -> bf16
    k_cvt_bf16<<<(int)NT,256,0,stream>>>(hidb, B.E_hid);
    // ctrl projection (256^2 8-wave derived-waits core)
    k_gemm_ctrl<<<dim3(17,NT/256),512,0,stream>>>(B.E_hid,1024, B.ctrlWT,1024,
                                                  B.ctrl, B.gbuf, B.bbuf, B.gateb, ctrlb);
    // P20 scan (f32 states, bf16 output)
    k_scan1<<<nb*128,256,0,stream>>>(hidb,dlog,theta,B.finals);
    k_scan2<<<nb*2, 256,0,stream>>>(dlog,theta,B.finals,B.carry,nb);
    k_scan3<<<nb*128,256,0,stream>>>(hidb,dlog,theta,B.carry,B.E_p20);
    k_rms_p20<<<(int)NT,256,0,stream>>>(B.E_p20,vns,B.fused);
    // causal conv + silu (raw)
    k_conv<<<dim3(12,NT/16),256,0,stream>>>(B.ctrl,qw,kw,vw,B.Qb,B.Kb,B.Vb);
    // p20 qkv projection (256^2 core) + ramp mix + l2norm (in-place into Q/K/V)
    k_gemm_qkv<<<dim3(12,NT/256),512,0,stream>>>(B.fused+1024,2048, B.p20WT,1024,
                                                 ramp, B.Qb,B.Kb,B.Vb);
    // gated delta rule (chunkwise WY)
    k_phase1<<<(int)(NT/4),64,0,stream>>>(B.Kb,B.Vb,B.gbuf,B.bbuf,B.uvT,B.Wrm,B.Mc,B.BcT);
    k_phase2<<<nb*64,64,0,stream>>>(B.Mc,B.BcT,B.Sst);
    k_phase3<<<(int)(NT/4),64,0,stream>>>(B.Qb,B.Kb,B.gbuf,B.uvT,B.Wrm,B.Sst,mns,B.fused);
    // out = sigmoid(gate) * (fused @ out_W + b)   (128^2 core)
    k_gemm<<<dim3(8,NT/128),256,0,stream>>>(B.fused,2048, B.outWT,2048,
                                            nullptr,outp,1024, 2048,1024, outb, B.gateb,1024);
  }
}

// Round 12
// 541.927 us; speedup vs baseline: 1.1559x; 1.1559x over previous
//
#include <hip/hip_runtime.h>
#include <hip/hip_bf16.h>
#include <stdint.h>

// Problem constants
#define SEQ  4096
#define NH   16
#define HD   64

typedef __attribute__((ext_vector_type(8))) short bf16x8;
typedef __attribute__((ext_vector_type(4))) float f32x4;

__device__ __forceinline__ float bf2f(unsigned short u){
  union{unsigned u;float f;} v; v.u = ((unsigned)u)<<16; return v.f;
}
__device__ __forceinline__ unsigned short f2bf(float f){
  union{float f;unsigned u;} v; v.f=f;
  return (unsigned short)((v.u + 0x7fffu + ((v.u>>16)&1u))>>16);
}
__device__ __forceinline__ float sigm(float x){ return 1.f/(1.f+__expf(-x)); }
__device__ __forceinline__ f32x4 mfma16(bf16x8 a, bf16x8 b, f32x4 c){
  return __builtin_amdgcn_mfma_f32_16x16x32_bf16(a,b,c,0,0,0);
}
__device__ __forceinline__ void gll16(const void* g, void* l){
  __builtin_amdgcn_global_load_lds((const __attribute__((address_space(1))) void*)g,
                                   (__attribute__((address_space(3))) void*)l, 16, 0, 0);
}

// ---------------- sentinel fill (encodes ws_size on insufficient-ws) ----------------
__global__ void k_fill(float* __restrict__ p, float v, long n){
  long i = (long)blockIdx.x*blockDim.x + threadIdx.x;
  long stride = (long)gridDim.x*blockDim.x;
  for (; i<n; i+=stride) p[i] = v;
}

// ---------------- transpose f32[R][Cin] -> bf16[Cpad][R], pad rows zeroed ----------------
__global__ void k_transpose(const float* __restrict__ in, unsigned short* __restrict__ out,
                            int R, int Cin, int Cpad){
  __shared__ float t[32][33];
  int cb = blockIdx.x*32, rb = blockIdx.y*32;
  int tx = threadIdx.x & 31, ty = threadIdx.x >> 5;
  for (int k=0;k<32;k+=8){
    int r = rb+ty+k, c = cb+tx;
    t[ty+k][tx] = (c<Cin) ? in[(long)r*Cin + c] : 0.f;
  }
  __syncthreads();
  for (int k=0;k<32;k+=8){
    int c = cb+ty+k, r = rb+tx;
    if (c<Cpad) out[(long)c*R + r] = f2bf(t[tx][ty+k]);
  }
}

// ======== MFMA GEMM core (128x128 tile, BK=32, 4 waves) — r10 proven 543us ========
// r11 post-mortem: 256^2 8-phase port regressed twice (1 blk/CU, no st_16x32
// swizzle, grid tail). GEMM chapter closed at this structure (~520 TF:
// LDS-BW-bound, 32KB reads/iter vs 78cy MFMA).
#define FOR16(F) F(0,0) F(0,1) F(0,2) F(0,3) F(1,0) F(1,1) F(1,2) F(1,3) \
                 F(2,0) F(2,1) F(2,2) F(2,3) F(3,0) F(3,1) F(3,2) F(3,3)
#define FOR4(F) F(0) F(1) F(2) F(3)
#define ACC(i,j) Ac##i##j

#define GEMM_CORE(A_,lda_,Bt_,ldb_,K_)                                         \
  __shared__ unsigned short Ab[3][4096];                                       \
  __shared__ unsigned short Bb[3][4096];                                       \
  const int tid=threadIdx.x, wid=tid>>6, l=tid&63;                             \
  const int nbx=(int)gridDim.x;                                               \
  const int nwg=nbx*(int)gridDim.y;                                           \
  int flat=(int)blockIdx.y*nbx+(int)blockIdx.x;                                \
  flat=(flat&7)*(nwg>>3)+(flat>>3);                                           \
  const long m0=(long)(flat/nbx)*128, n0=(long)(flat%nbx)*128;                 \
  const int nk=(K_)>>5;                                                        \
  const int wm=(wid>>1)*64, wn=(wid&1)*64;                                     \
  const int srow0 = tid>>2;                                                    \
  const int schunk = (((tid&3) ^ ((tid>>4)&3))<<3);                            \
  const unsigned short* gA0 = (A_) + (m0+srow0)*(lda_) + schunk;               \
  const unsigned short* gA1 = (A_) + (m0+64+srow0)*(lda_) + schunk;            \
  const unsigned short* gB0 = (Bt_) + (n0+srow0)*(ldb_) + schunk;              \
  const unsigned short* gB1 = (Bt_) + (n0+64+srow0)*(ldb_) + schunk;           \
  const int ldst0 = tid*16, ldst1 = 4096 + tid*16;                             \
  f32x4 Ac00={0.f,0.f,0.f,0.f};                                                \
  f32x4 Ac01=Ac00,Ac02=Ac00,Ac03=Ac00,Ac10=Ac00,Ac11=Ac00,Ac12=Ac00,           \
        Ac13=Ac00,Ac20=Ac00,Ac21=Ac00,Ac22=Ac00,Ac23=Ac00,Ac30=Ac00,           \
        Ac31=Ac00,Ac32=Ac00,Ac33=Ac00;                                         \
  gll16(gA0, (char*)&Ab[0][0]+ldst0); gll16(gA1, (char*)&Ab[0][0]+ldst1);      \
  gll16(gB0, (char*)&Bb[0][0]+ldst0); gll16(gB1, (char*)&Bb[0][0]+ldst1);      \
  gA0+=32; gA1+=32; gB0+=32; gB1+=32;                                          \
  gll16(gA0, (char*)&Ab[1][0]+ldst0); gll16(gA1, (char*)&Ab[1][0]+ldst1);      \
  gll16(gB0, (char*)&Bb[1][0]+ldst0); gll16(gB1, (char*)&Bb[1][0]+ldst1);      \
  gA0+=32; gA1+=32; gB0+=32; gB1+=32;                                          \
  int rb=0, sb=2;                                                              \
  const int sxor = ((l>>2)&3)<<4;                                              \
  const int rao0 = (wm+(l&15))*64 + (((l>>4)<<4) ^ sxor);                      \
  const int rbo0 = (wn+(l&15))*64 + (((l>>4)<<4) ^ sxor);                      \
  for (int kt=0; kt<nk; ++kt){                                                 \
    if (kt+1<nk) { asm volatile("s_waitcnt vmcnt(4)" ::: "memory"); }          \
    else         { asm volatile("s_waitcnt vmcnt(0)" ::: "memory"); }          \
    __builtin_amdgcn_sched_barrier(0);                                         \
    __builtin_amdgcn_s_barrier();                                              \
    __builtin_amdgcn_sched_barrier(0);                                         \
    if (kt+2<nk){                                                              \
      gll16(gA0, (char*)&Ab[sb][0]+ldst0); gll16(gA1, (char*)&Ab[sb][0]+ldst1);\
      gll16(gB0, (char*)&Bb[sb][0]+ldst0); gll16(gB1, (char*)&Bb[sb][0]+ldst1);\
      gA0+=32; gA1+=32; gB0+=32; gB1+=32;                                      \
    }                                                                          \
    const char* Apt=(const char*)&Ab[rb][0];                                   \
    const char* Bpt=(const char*)&Bb[rb][0];                                   \
    bf16x8 af0=*(const bf16x8*)(Apt+rao0);      bf16x8 bf0=*(const bf16x8*)(Bpt+rbo0);      \
    bf16x8 af1=*(const bf16x8*)(Apt+rao0+1024); bf16x8 bf1=*(const bf16x8*)(Bpt+rbo0+1024); \
    bf16x8 af2=*(const bf16x8*)(Apt+rao0+2048); bf16x8 bf2=*(const bf16x8*)(Bpt+rbo0+2048); \
    bf16x8 af3=*(const bf16x8*)(Apt+rao0+3072); bf16x8 bf3=*(const bf16x8*)(Bpt+rbo0+3072); \
    __builtin_amdgcn_s_setprio(1);                                             \
    Ac00=mfma16(af0,bf0,Ac00); Ac01=mfma16(af0,bf1,Ac01);                      \
    Ac02=mfma16(af0,bf2,Ac02); Ac03=mfma16(af0,bf3,Ac03);                      \
    Ac10=mfma16(af1,bf0,Ac10); Ac11=mfma16(af1,bf1,Ac11);                      \
    Ac12=mfma16(af1,bf2,Ac12); Ac13=mfma16(af1,bf3,Ac13);                      \
    Ac20=mfma16(af2,bf0,Ac20); Ac21=mfma16(af2,bf1,Ac21);                      \
    Ac22=mfma16(af2,bf2,Ac22); Ac23=mfma16(af2,bf3,Ac23);                      \
    Ac30=mfma16(af3,bf0,Ac30); Ac31=mfma16(af3,bf1,Ac31);                      \
    Ac32=mfma16(af3,bf2,Ac32); Ac33=mfma16(af3,bf3,Ac33);                      \
    __builtin_amdgcn_s_setprio(0);                                             \
    rb = (rb==2)?0:rb+1; sb = (sb==2)?0:sb+1;                                  \
  }

// ---- variant 1: generic, f32 or bf16 out, +bias, *gate(pre-sigmoided bf16) ----
__global__ __launch_bounds__(256,2) void k_gemm(
  const unsigned short* __restrict__ A, int lda,
  const unsigned short* __restrict__ Bt, int ldb,
  unsigned short* Cb, float* Cf, int ldc,
  int K, int Nvalid,
  const float* __restrict__ bias,
  const unsigned short* __restrict__ gate, int gld)
{
  GEMM_CORE(A, lda, Bt, ldb, K)
#define EPI_GEN(mi,ni) {                                                       \
  const int gn=(int)n0+wn+ni*16+(l&15);                                        \
  if (gn<Nvalid){                                                              \
    _Pragma("unroll") for(int r=0;r<4;r++){                                    \
      const long gm=m0+wm+mi*16+((l>>4)<<2)+r;                                 \
      float v=ACC(mi,ni)[r];                                                   \
      if(bias) v+=bias[gn];                                                    \
      if(gate) v*=bf2f(gate[gm*gld+gn]);                                       \
      if(Cb) Cb[gm*ldc+gn]=f2bf(v); else Cf[gm*ldc+gn]=v; } } }
  FOR16(EPI_GEN)
#undef EPI_GEN
}

// ---- variant 2: ctrl projection ----
__global__ __launch_bounds__(256,2) void k_gemm_ctrl(
  const unsigned short* __restrict__ A, int lda,
  const unsigned short* __restrict__ Bt, int ldb,
  unsigned short* __restrict__ ctrl,
  float* __restrict__ gbuf, float* __restrict__ bbuf,
  unsigned short* __restrict__ gateb,
  const float* __restrict__ bias)
{
  GEMM_CORE(A, lda, Bt, ldb, 1024)
#define EPI_CTRL(mi,ni) {                                                      \
  const int gn=(int)n0+wn+ni*16+(l&15);                                        \
  if (gn<4128){                                                                \
    const float bs=bias[gn];                                                   \
    _Pragma("unroll") for(int r=0;r<4;r++){                                    \
      const long gm=m0+wm+mi*16+((l>>4)<<2)+r;                                 \
      float v=ACC(mi,ni)[r]+bs;                                                \
      if (gn<3072)      ctrl[gm*3072+gn]=f2bf(v);                              \
      else if (gn<3088) gbuf[gm*16+(gn-3072)]=                                 \
                          (v>=0.f)?-log1pf(__expf(-v)):(v-log1pf(__expf(v)));  \
      else if (gn<3104) bbuf[gm*16+(gn-3088)]=sigm(v);                         \
      else              gateb[gm*1024+(gn-3104)]=f2bf(sigm(v)); } } }
  FOR16(EPI_CTRL)
#undef EPI_CTRL
}

// ---- variant 3: p20 qkv projection, fused mix + per-head l2norm ----
__global__ __launch_bounds__(256,2) void k_gemm_qkv(
  const unsigned short* __restrict__ A, int lda,
  const unsigned short* __restrict__ Bt, int ldb,
  const float* __restrict__ ramp,
  unsigned short* __restrict__ Qb, unsigned short* __restrict__ Kb,
  unsigned short* __restrict__ Vb)
{
  GEMM_CORE(A, lda, Bt, ldb, 1024)
  const int seg = (int)((n0 + wn) >> 10);
  unsigned short* Ob = (seg==0)?Qb:((seg==1)?Kb:Vb);
  const int dc0=((int)n0+wn+0*16+(l&15))&1023; const float sr0=sigm(ramp[dc0]);
  const int dc1=((int)n0+wn+1*16+(l&15))&1023; const float sr1=sigm(ramp[dc1]);
  const int dc2=((int)n0+wn+2*16+(l&15))&1023; const float sr2=sigm(ramp[dc2]);
  const int dc3=((int)n0+wn+3*16+(l&15))&1023; const float sr3=sigm(ramp[dc3]);
#define EPI_QKV(mi) {                                                          \
  _Pragma("unroll") for(int r=0;r<4;r++){                                      \
    const long gm=m0+wm+mi*16+((l>>4)<<2)+r;                                   \
    float v0=bf2f(Ob[gm*1024+dc0])+sr0*ACC(mi,0)[r];                           \
    float v1=bf2f(Ob[gm*1024+dc1])+sr1*ACC(mi,1)[r];                           \
    float v2=bf2f(Ob[gm*1024+dc2])+sr2*ACC(mi,2)[r];                           \
    float v3=bf2f(Ob[gm*1024+dc3])+sr3*ACC(mi,3)[r];                           \
    if (seg<2){                                                                \
      float ss=v0*v0+v1*v1+v2*v2+v3*v3;                                        \
      ss+=__shfl_xor(ss,1); ss+=__shfl_xor(ss,2);                              \
      ss+=__shfl_xor(ss,4); ss+=__shfl_xor(ss,8);                              \
      float rs=rsqrtf(ss+1e-6f); v0*=rs; v1*=rs; v2*=rs; v3*=rs; }             \
    Ob[gm*1024+dc0]=f2bf(v0); Ob[gm*1024+dc1]=f2bf(v1);                        \
    Ob[gm*1024+dc2]=f2bf(v2); Ob[gm*1024+dc3]=f2bf(v3); } }
  FOR4(EPI_QKV)
#undef EPI_QKV
}

// ---------------- P20 scan (chunked) ----------------
// r12: scan1 fused with the f32->bf16 hidden conversion (k_cvt eliminated):
// it already reads every element; emit coalesced ushort2 stores.
__global__ void k_scan1(const float* __restrict__ hidden, const float* __restrict__ dlog,
                        const float* __restrict__ theta, float2* __restrict__ finals,
                        unsigned short* __restrict__ hid_bf){
  int idx = blockIdx.x*256 + threadIdx.x;      // [b][chunk][ch]
  int ch = idx & 511; int chunk = (idx>>9) & 63; int b = idx>>15;
  float e = __expf(dlog[ch]); float r = __expf(-e);
  float th = theta[ch]; float ar = r*__cosf(th), ai = r*__sinf(th);
  long toff = (long)b*SEQ + chunk*64;
  const float2* src = (const float2*)hidden + toff*512 + ch;
  unsigned short* dst = hid_bf + toff*1024 + 2*ch;
  float sr=0.f, si=0.f;
  for (int j=0;j<64;j++){
    float2 u = src[(long)j*512];
    ushort2 hb; hb.x=f2bf(u.x); hb.y=f2bf(u.y);
    *(ushort2*)(dst + (long)j*1024) = hb;
    float nr = sr*ar - si*ai + u.x;
    si = sr*ai + si*ar + u.y; sr = nr;
  }
  finals[idx] = make_float2(sr,si);
}
__global__ void k_scan2(const float* __restrict__ dlog, const float* __restrict__ theta,
                        const float2* __restrict__ finals, float2* __restrict__ carry, int nb){
  int idx = blockIdx.x*256+threadIdx.x; if (idx>=nb*512) return;
  int ch = idx & 511, b = idx>>9;
  float e = __expf(dlog[ch]); float r64 = __expf(-64.f*e);
  float ang = fmodf(64.f*theta[ch], 6.2831853071795864f);
  float cr = r64*__cosf(ang), ci = r64*__sinf(ang);
  float pr=0.f, pi=0.f;
  for (int c=0;c<64;c++){
    long o = ((long)b*64 + c)*512 + ch;
    carry[o] = make_float2(pr,pi);
    float2 f = finals[o];
    float nr = pr*cr - pi*ci + f.x;
    pi = pr*ci + pi*cr + f.y; pr = nr;
  }
}
__global__ void k_scan3(const float* __restrict__ hidden, const float* __restrict__ dlog,
                        const float* __restrict__ theta, const float2* __restrict__ carry,
                        unsigned short* __restrict__ p20){
  int idx = blockIdx.x*256 + threadIdx.x;
  int ch = idx & 511; int chunk = (idx>>9) & 63; int b = idx>>15;
  float e = __expf(dlog[ch]); float r = __expf(-e);
  float th = theta[ch]; float ar = r*__cosf(th), ai = r*__sinf(th);
  long toff = (long)b*SEQ + chunk*64;
  const float2* src = (const float2*)hidden + toff*512 + ch;
  unsigned short* dst = p20 + toff*1024 + 2*ch;
  float2 c0 = carry[idx];
  float sr=c0.x, si=c0.y;
  for (int j=0;j<64;j++){
    float2 u = src[(long)j*512];
    float nr = sr*ar - si*ai + u.x;
    si = sr*ai + si*ar + u.y; sr = nr;
    ushort2 o; o.x=f2bf(sr); o.y=f2bf(si);
    *(ushort2*)(dst + (long)j*1024) = o;
  }
}

// ---------------- rmsnorm(p20 bf16) -> fused[:,1024:2048] bf16 ----------------
__global__ __launch_bounds__(256) void k_rms_p20(const unsigned short* __restrict__ p20,
                        const float* __restrict__ vns, unsigned short* __restrict__ fused){
  long t = blockIdx.x;
  int d = threadIdx.x*4;
  ushort4 xu = *(const ushort4*)(p20 + t*1024 + d);
  float x0=bf2f(xu.x), x1=bf2f(xu.y), x2=bf2f(xu.z), x3=bf2f(xu.w);
  float ss = x0*x0 + x1*x1 + x2*x2 + x3*x3;
  for (int o=1;o<64;o<<=1) ss += __shfl_xor(ss, o);
  __shared__ float red[4];
  if ((threadIdx.x&63)==0) red[threadIdx.x>>6] = ss;
  __syncthreads();
  ss = red[0]+red[1]+red[2]+red[3];
  float rs = rsqrtf(ss*(1.f/1024.f) + 1e-6f);
  float4 s4 = *(const float4*)(vns + d);
  ushort4 o4;
  o4.x = f2bf(x0*rs*s4.x); o4.y = f2bf(x1*rs*s4.y);
  o4.z = f2bf(x2*rs*s4.z); o4.w = f2bf(x3*rs*s4.w);
  *(ushort4*)(fused + t*2048 + 1024 + d) = o4;
}

// ---------------- causal depthwise conv + SiLU (raw, pre-mix) ----------------
__global__ __launch_bounds__(256) void k_conv(const unsigned short* __restrict__ ctrl,
   const float* __restrict__ qw, const float* __restrict__ kw, const float* __restrict__ vw,
   unsigned short* __restrict__ Q, unsigned short* __restrict__ Kb, unsigned short* __restrict__ Vb){
  __shared__ unsigned short pan[19][256];
  int panel = blockIdx.x;            // 0..11
  int tb = blockIdx.y;
  int b = tb >> 8; int s0 = (tb & 255) * 16;
  int seg = panel >> 2; int d = (panel & 3)*256 + threadIdx.x;
  int c0 = panel*256;
  long base = (long)b*SEQ*3072;
  for (int rr=0; rr<19; rr++){
    int s = s0 - 3 + rr;
    pan[rr][threadIdx.x] = (s>=0) ? ctrl[base + (long)s*3072 + c0 + threadIdx.x] : (unsigned short)0;
  }
  __syncthreads();
  const float* cw = (seg==0)?qw:((seg==1)?kw:vw);
  float w0=cw[d*4], w1=cw[d*4+1], w2=cw[d*4+2], w3=cw[d*4+3];
  unsigned short* Ob = (seg==0)?Q:((seg==1)?Kb:Vb);
  for (int tk=0; tk<16; tk++){
    long t = (long)b*SEQ + s0 + tk;
    float x = bf2f(pan[tk][threadIdx.x])*w0 + bf2f(pan[tk+1][threadIdx.x])*w1
            + bf2f(pan[tk+2][threadIdx.x])*w2 + bf2f(pan[tk+3][threadIdx.x])*w3;
    x = x * sigm(x);  // silu
    Ob[t*1024 + d] = f2bf(x);
  }
}

// ---------------- delta rule phase 1: per head-chunk WY decomposition ----------------
__global__ __launch_bounds__(64,2) void k_phase1(
    const unsigned short* __restrict__ Kg, const unsigned short* __restrict__ Vg,
    const float* __restrict__ g, const float* __restrict__ beta,
    unsigned short* __restrict__ uvT, unsigned short* __restrict__ Wrm,
    unsigned short* __restrict__ Mc, unsigned short* __restrict__ BcT){
  __shared__ unsigned short Kc[64*64];     // swizzled rows
  __shared__ unsigned short Vc[64*64];     // linear
  __shared__ float Af[64*64];              // A (f32); first 8KB reused as K'^T bf16 after solve
  __shared__ unsigned short uTb[64*72];    // u_v^T [v][j] bf16 (stride 72)
  __shared__ unsigned short wTb[64*72];    // W^T  [kd][j] bf16
  __shared__ float Gs[64], betl[64], bgam[64], decC[64];

  int bid = blockIdx.x; int bh = bid>>6, c = bid&63;
  int blocal = bh>>4, h = bh&15;
  long t0 = (long)blocal*SEQ + c*64;
  int l = threadIdx.x;
  long cbase = (long)bid*4096;

  // cumulative log-decay (within chunk)
  float G = g[(t0+l)*16 + h];
  for (int o=1;o<64;o<<=1){ float n = __shfl_up(G,o); if (l>=o) G += n; }
  float bl = beta[(t0+l)*16+h];
  Gs[l]=G; betl[l]=bl; bgam[l]=bl*__expf(G);
  float G63 = __shfl(G,63);
  decC[l] = __expf(G63 - G);
  float GamC = __expf(G63);

  // stage K (swizzled via pre-swizzled global source) and V (linear)
  for (int it=0; it<8; it++){
    int bo = it*1024 + l*16;
    int row = bo>>7, bib = bo&127;
    int sb2 = bib ^ ((row&7)<<4);
    gll16(Kg + (t0+row)*1024 + h*64 + (sb2>>1),  (char*)Kc + bo);
    gll16(Vg + (t0+row)*1024 + h*64 + (bib>>1), (char*)Vc + bo);
  }
  __syncthreads();

  // K K^T -> A = strict_lower(beta_i * (k_i.k_j) * exp(Gi-Gj))  (f32)
  bf16x8 kf[2][4];
  {
    int rr = l&15;
    #pragma unroll
    for (int t=0;t<4;t++)
      #pragma unroll
      for (int h2=0;h2<2;h2++){
        int row = t*16 + rr;
        int byt = row*128 + ((h2*64 + (l>>4)*16) ^ ((row&7)<<4));
        kf[h2][t] = *(const bf16x8*)((const char*)Kc + byt);
      }
  }
  #pragma unroll
  for (int ti=0;ti<4;ti++){
    #pragma unroll
    for (int tj=0;tj<4;tj++){
      f32x4 a = {0.f,0.f,0.f,0.f};
      a = mfma16(kf[0][ti], kf[0][tj], a);
      a = mfma16(kf[1][ti], kf[1][tj], a);
      int j = tj*16 + (l&15);
      float Gj = Gs[j];
      #pragma unroll
      for (int r=0;r<4;r++){
        int i = ti*16 + ((l>>4)<<2) + r;
        Af[i*64+j] = (j<i) ? betl[i]*a[r]*__expf(Gs[i]-Gj) : 0.f;
      }
    }
  }
  __syncthreads();

  // forward substitution f32, lane = column, state in REGISTERS (r5: -200us).
  float ww[64];
  {
    float uu[64];
    #pragma unroll
    for (int i=0;i<64;i++){
      float ua = betl[i]*bf2f(Vc[i*64 + l]);
      float wa = bgam[i]*bf2f(*(const unsigned short*)((const char*)Kc + i*128 + ((2*l) ^ ((i&7)<<4))));
      #pragma unroll
      for (int j=0;j<i;j++){
        float av = Af[i*64+j];
        ua -= av*uu[j];
        wa -= av*ww[j];
      }
      uu[i] = ua; ww[i] = wa;
    }
    #pragma unroll
    for (int i=0;i<64;i+=4){
      short4 pu, pw;
      pu.x=(short)f2bf(uu[i]);   pu.y=(short)f2bf(uu[i+1]);
      pu.z=(short)f2bf(uu[i+2]); pu.w=(short)f2bf(uu[i+3]);
      pw.x=(short)f2bf(ww[i]);   pw.y=(short)f2bf(ww[i+1]);
      pw.z=(short)f2bf(ww[i+2]); pw.w=(short)f2bf(ww[i+3]);
      *(short4*)&uTb[l*72+i] = pu;
      *(short4*)&wTb[l*72+i] = pw;
    }
  }
  __syncthreads();

  // build K'^T[kd][j] = exp(G63-Gj)*K[j][kd] into first 8KB of Af (bf16, swizzled rows)
  unsigned short* KTp = (unsigned short*)Af;
  for (int j=0;j<64;j++){
    float kv = bf2f(*(const unsigned short*)((const char*)Kc + j*128 + ((2*l) ^ ((j&7)<<4))));
    *(unsigned short*)((char*)KTp + l*128 + ((2*j) ^ ((l&7)<<4))) = f2bf(decC[j]*kv);
  }
  __syncthreads();

  auto ldfragKT = [&](int t, int h2)->bf16x8{
    int row = t*16 + (l&15);
    int byt = row*128 + ((h2*64 + (l>>4)*16) ^ ((row&7)<<4));
    return *(const bf16x8*)((const char*)KTp + byt);
  };
  auto ldfrag72 = [&](const unsigned short* base, int nrow, int h2)->bf16x8{
    return *(const bf16x8*)(base + nrow*72 + h2*32 + ((l>>4)<<3));
  };

  // M_c = GamC*I - K'^T W   and   B_c = K'^T u_v (stored [v][kd] bf16)
  #pragma unroll
  for (int to=0; to<4; to++){
    bf16x8 a0 = ldfragKT(to,0), a1 = ldfragKT(to,1);
    #pragma unroll
    for (int tn=0; tn<4; tn++){
      f32x4 accv = {0.f,0.f,0.f,0.f};
      accv = mfma16(a0, ldfrag72(wTb, tn*16+(l&15), 0), accv);
      accv = mfma16(a1, ldfrag72(wTb, tn*16+(l&15), 1), accv);
      int col = tn*16 + (l&15);
      #pragma unroll
      for (int r=0;r<4;r++){
        int row = to*16 + ((l>>4)<<2) + r;
        Mc[cbase + row*64 + col] = f2bf(((row==col)? GamC : 0.f) - accv[r]);
      }
    }
    #pragma unroll
    for (int tv=0; tv<4; tv++){
      f32x4 accv = {0.f,0.f,0.f,0.f};
      accv = mfma16(a0, ldfrag72(uTb, tv*16+(l&15), 0), accv);
      accv = mfma16(a1, ldfrag72(uTb, tv*16+(l&15), 1), accv);
      int v = tv*16 + (l&15);
      int k0 = to*16 + ((l>>4)<<2);
      short4 p;
      p.x=(short)f2bf(accv[0]); p.y=(short)f2bf(accv[1]);
      p.z=(short)f2bf(accv[2]); p.w=(short)f2bf(accv[3]);
      *(short4*)&BcT[cbase + v*64 + k0] = p;
    }
  }

  // dump u_v^T [v][j] (cross-lane, via LDS) and W row-major [i][kd] (lane-local regs)
  #pragma unroll
  for (int rr=0; rr<64; rr++){
    uvT[cbase + rr*64 + l] = uTb[rr*72 + l];
    Wrm[cbase + rr*64 + l] = f2bf(ww[rr]);
  }
}

// ---------------- delta rule phase 2: per-head chunk-state chain (V-split x4) ----------------
__global__ __launch_bounds__(64,2) void k_phase2(
    const unsigned short* __restrict__ Mc, const unsigned short* __restrict__ BcT,
    unsigned short* __restrict__ Sst){
  __shared__ unsigned short ST[16*64];   // S^T slice [16 v][64 kd] bf16, swizzled
  const int bh = blockIdx.x>>2, vq = blockIdx.x&3;
  const int l = threadIdx.x;
  const int vloc = l&15;
  const int v = vq*16 + vloc;
  f32x4 Ac0={0.f,0.f,0.f,0.f};
  f32x4 Ac1=Ac0, Ac2=Ac0, Ac3=Ac0;
  for (int c=0;c<64;c++){
    long cbase = ((long)bh*64 + c)*4096;
#define P2ST(ti,A) { int kd0 = ti*16 + ((l>>4)<<2); short4 p;                  \
      p.x=(short)f2bf(A[0]); p.y=(short)f2bf(A[1]);                            \
      p.z=(short)f2bf(A[2]); p.w=(short)f2bf(A[3]);                            \
      *(short4*)&Sst[cbase + (long)v*64 + kd0] = p;                            \
      *(short4*)((char*)ST + vloc*128 + ((2*kd0) ^ ((vloc&7)<<4))) = p; }
    P2ST(0,Ac0) P2ST(1,Ac1) P2ST(2,Ac2) P2ST(3,Ac3)
#undef P2ST
    __syncthreads();
    const unsigned short* Mp = Mc + cbase;
    bf16x8 m0a = *(const bf16x8*)(Mp + ( 0+(l&15))*64 + (l>>4)*8);
    bf16x8 m0b = *(const bf16x8*)(Mp + ( 0+(l&15))*64 + 32 + (l>>4)*8);
    bf16x8 m1a = *(const bf16x8*)(Mp + (16+(l&15))*64 + (l>>4)*8);
    bf16x8 m1b = *(const bf16x8*)(Mp + (16+(l&15))*64 + 32 + (l>>4)*8);
    bf16x8 m2a = *(const bf16x8*)(Mp + (32+(l&15))*64 + (l>>4)*8);
    bf16x8 m2b = *(const bf16x8*)(Mp + (32+(l&15))*64 + 32 + (l>>4)*8);
    bf16x8 m3a = *(const bf16x8*)(Mp + (48+(l&15))*64 + (l>>4)*8);
    bf16x8 m3b = *(const bf16x8*)(Mp + (48+(l&15))*64 + 32 + (l>>4)*8);
#define P2LD(ti,A) { short4 bv = *(const short4*)&BcT[cbase + (long)v*64 + ti*16 + ((l>>4)<<2)]; \
      A[0]=bf2f((unsigned short)bv.x); A[1]=bf2f((unsigned short)bv.y);        \
      A[2]=bf2f((unsigned short)bv.z); A[3]=bf2f((unsigned short)bv.w); }
    P2LD(0,Ac0) P2LD(1,Ac1) P2LD(2,Ac2) P2LD(3,Ac3)
#undef P2LD
    bf16x8 sfa = *(const bf16x8*)((const char*)ST + vloc*128 + (((l>>4)*16) ^ ((vloc&7)<<4)));
    bf16x8 sfb = *(const bf16x8*)((const char*)ST + vloc*128 + ((64+(l>>4)*16) ^ ((vloc&7)<<4)));
    Ac0 = mfma16(m0a, sfa, Ac0); Ac0 = mfma16(m0b, sfb, Ac0);
    Ac1 = mfma16(m1a, sfa, Ac1); Ac1 = mfma16(m1b, sfb, Ac1);
    Ac2 = mfma16(m2a, sfa, Ac2); Ac2 = mfma16(m2b, sfb, Ac2);
    Ac3 = mfma16(m3a, sfa, Ac3); Ac3 = mfma16(m3b, sfb, Ac3);
    __syncthreads();
  }
}

// ---------------- delta rule phase 3: outputs + head rmsnorm -> fused[:,0:1024] ----------------
__global__ __launch_bounds__(64,2) void k_phase3(
  const unsigned short* __restrict__ Qg, const unsigned short* __restrict__ Kg,
  const float* __restrict__ g,
  const unsigned short* __restrict__ uvT, const unsigned short* __restrict__ Wrm,
  const unsigned short* __restrict__ Sst, const float* __restrict__ mns,
  unsigned short* __restrict__ fused){
  __shared__ unsigned short ST[64*64];
  __shared__ unsigned short QKl[64*64];
  __shared__ unsigned short uT[64*64];
  __shared__ float Gs[64];
  int bid = blockIdx.x; int bh = bid>>6, c = bid&63;
  int blocal = bh>>4, h = bh&15; long t0 = (long)blocal*SEQ + c*64;
  long cbase = (long)bid*4096;
  int l = threadIdx.x;

  float G = g[(t0+l)*16+h];
  for (int o=1;o<64;o<<=1){ float n=__shfl_up(G,o); if(l>=o) G+=n; }
  Gs[l]=G;

  // load S_0^T (bf16) into LDS (swizzled)
  #pragma unroll
  for (int it=0; it<16; it++){
    int flat = it*256 + l*4;
    int v = flat>>6, kd0 = flat&63;
    short4 s4 = *(const short4*)&Sst[cbase + flat];
    *(short4*)((char*)ST + v*128 + ((2*kd0) ^ ((v&7)<<4))) = s4;
  }
  __syncthreads();

  bf16x8 qf[2][4], kfr[2][4], sf[2][4];
  #pragma unroll
  for (int t=0;t<4;t++){
    long tr = t0 + t*16 + (l&15);
    qf[0][t]  = *(const bf16x8*)(Qg + tr*1024 + h*64 + (l>>4)*8);
    qf[1][t]  = *(const bf16x8*)(Qg + tr*1024 + h*64 + 32 + (l>>4)*8);
    kfr[0][t] = *(const bf16x8*)(Kg + tr*1024 + h*64 + (l>>4)*8);
    kfr[1][t] = *(const bf16x8*)(Kg + tr*1024 + h*64 + 32 + (l>>4)*8);
    int v = t*16 + (l&15);
    sf[0][t] = *(const bf16x8*)((const char*)ST + v*128 + (((l>>4)*16) ^ ((v&7)<<4)));
    sf[1][t] = *(const bf16x8*)((const char*)ST + v*128 + ((64+(l>>4)*16) ^ ((v&7)<<4)));
  }

  // QS = Q @ S0
  f32x4 qs[4][4];
  #pragma unroll
  for (int ti=0;ti<4;ti++)
    #pragma unroll
    for (int tj=0;tj<4;tj++){
      f32x4 a = {0.f,0.f,0.f,0.f};
      a = mfma16(qf[0][ti], sf[0][tj], a);
      a = mfma16(qf[1][ti], sf[1][tj], a);
      qs[ti][tj] = a;
    }

  // QK (masked, decayed) -> LDS
  #pragma unroll
  for (int ti=0;ti<4;ti++)
    #pragma unroll
    for (int tj=0;tj<4;tj++){
      f32x4 a = {0.f,0.f,0.f,0.f};
      a = mfma16(qf[0][ti], kfr[0][tj], a);
      a = mfma16(qf[1][ti], kfr[1][tj], a);
      int j = tj*16 + (l&15);
      float Gj = Gs[j];
      #pragma unroll
      for (int r=0;r<4;r++){
        int i = ti*16 + ((l>>4)<<2) + r;
        float v = (j<=i)? a[r]*__expf(Gs[i]-Gj) : 0.f;
        *(unsigned short*)((char*)QKl + i*128 + ((2*j) ^ ((i&7)<<4))) = f2bf(v);
      }
    }

  // WS = W @ S0 ;  u^T = u_v^T - WS^T -> LDS
  #pragma unroll
  for (int ti=0; ti<4; ti++){
    int irow = ti*16 + (l&15);
    bf16x8 w0 = *(const bf16x8*)(Wrm + cbase + irow*64 + (l>>4)*8);
    bf16x8 w1 = *(const bf16x8*)(Wrm + cbase + irow*64 + 32 + (l>>4)*8);
    #pragma unroll
    for (int tj=0; tj<4; tj++){
      f32x4 a = {0.f,0.f,0.f,0.f};
      a = mfma16(w0, sf[0][tj], a);
      a = mfma16(w1, sf[1][tj], a);
      int v = tj*16 + (l&15);
      int i0 = ti*16 + ((l>>4)<<2);
      short4 uv4 = *(const short4*)(uvT + cbase + (long)v*64 + i0);
      short4 p;
      p.x=(short)f2bf(bf2f((unsigned short)uv4.x) - a[0]);
      p.y=(short)f2bf(bf2f((unsigned short)uv4.y) - a[1]);
      p.z=(short)f2bf(bf2f((unsigned short)uv4.z) - a[2]);
      p.w=(short)f2bf(bf2f((unsigned short)uv4.w) - a[3]);
      *(short4*)((char*)uT + v*128 + ((2*i0) ^ ((v&7)<<4))) = p;
    }
  }
  __syncthreads();

  // o = Gam_i * QS + QK @ u ; then head rmsnorm; write
  float mscale[4];
  #pragma unroll
  for (int tj=0;tj<4;tj++) mscale[tj] = mns[tj*16 + (l&15)];
  #pragma unroll
  for (int ti=0; ti<4; ti++){
    int row = ti*16 + (l&15);
    bf16x8 qk0 = *(const bf16x8*)((const char*)QKl + row*128 + (((l>>4)*16) ^ ((row&7)<<4)));
    bf16x8 qk1 = *(const bf16x8*)((const char*)QKl + row*128 + ((64+(l>>4)*16) ^ ((row&7)<<4)));
    #pragma unroll
    for (int tj=0; tj<4; tj++){
      int v = tj*16 + (l&15);
      bf16x8 u0 = *(const bf16x8*)((const char*)uT + v*128 + (((l>>4)*16) ^ ((v&7)<<4)));
      bf16x8 u1 = *(const bf16x8*)((const char*)uT + v*128 + ((64+(l>>4)*16) ^ ((v&7)<<4)));
      f32x4 a;
      #pragma unroll
      for (int r=0;r<4;r++){
        float gam = __expf(Gs[ti*16 + ((l>>4)<<2) + r]);
        a[r] = qs[ti][tj][r]*gam;
      }
      a = mfma16(qk0,u0,a);
      a = mfma16(qk1,u1,a);
      qs[ti][tj] = a;
    }
  }
  #pragma unroll
  for (int ti=0; ti<4; ti++){
    #pragma unroll
    for (int r=0; r<4; r++){
      float ss = 0.f;
      #pragma unroll
      for (int tj=0;tj<4;tj++){ float v = qs[ti][tj][r]*0.125f; ss += v*v; }
      ss += __shfl_xor(ss,1); ss += __shfl_xor(ss,2); ss += __shfl_xor(ss,4); ss += __shfl_xor(ss,8);
      float rs = rsqrtf(ss*(1.f/64.f) + 1e-6f);
      long t = t0 + ti*16 + ((l>>4)<<2) + r;
      #pragma unroll
      for (int tj=0;tj<4;tj++){
        float on = qs[ti][tj][r]*0.125f*rs*mscale[tj];
        fused[t*2048 + h*64 + tj*16 + (l&15)] = f2bf(on);
      }
    }
  }
}

// =======================================================================
extern "C" void kernel_launch(void* const* d_in, const int* in_sizes, int n_in,
                              void* d_out, int out_size, void* d_ws, size_t ws_size,
                              hipStream_t stream){
  (void)in_sizes; (void)n_in;
  const float* hidden = (const float*)d_in[0];
  const float* dlog   = (const float*)d_in[1];
  const float* theta  = (const float*)d_in[2];
  const float* ctrlW  = (const float*)d_in[3];
  const float* ctrlb  = (const float*)d_in[4];
  const float* p20cW  = (const float*)d_in[5];
  const float* qw     = (const float*)d_in[6];
  const float* kw     = (const float*)d_in[7];
  const float* vw     = (const float*)d_in[8];
  const float* mns    = (const float*)d_in[9];
  const float* vns    = (const float*)d_in[10];
  const float* ramp   = (const float*)d_in[11];
  const float* outW   = (const float*)d_in[12];
  const float* outb   = (const float*)d_in[13];
  float* out = (float*)d_out;

  struct Bufs {
    unsigned short *ctrl, *uvT, *Wrm, *Mc;
    unsigned short *Qb, *Kb, *Vb, *fused;
    unsigned short *E_hid, *E_p20, *BcT;
    unsigned short *Sst, *gateb, *ctrlWT, *p20WT, *outWT;
    float2 *finals, *carry; float *gbuf, *bbuf;
    size_t need;
  };
  auto mk = [&](size_t NT)->Bufs{
    Bufs B; size_t off=0;
    auto tk=[&](size_t n)->char*{ char* p=(char*)d_ws+off; off += (n+255)&~(size_t)255; return p; };
    char* Rctrl = tk(NT*3072*2);                       // ctrl -> uvT|Wrm|Mc (byte-exact)
    B.ctrl=(unsigned short*)Rctrl;
    B.uvT=(unsigned short*)Rctrl; B.Wrm=B.uvT + NT*1024; B.Mc=B.Wrm + NT*1024;
    char* Rqkv = tk(NT*1024*2*3);
    B.Qb=(unsigned short*)Rqkv; B.Kb=B.Qb+NT*1024; B.Vb=B.Kb+NT*1024;
    B.fused=(unsigned short*)tk(NT*2048*2);
    char* RE = tk(NT*1024*2);                          // hid_bf -> p20(bf16) -> BcT
    B.E_hid=(unsigned short*)RE; B.E_p20=(unsigned short*)RE; B.BcT=(unsigned short*)RE;
    B.Sst=(unsigned short*)tk(NT*1024*2);
    B.gateb=(unsigned short*)tk(NT*1024*2);
    B.ctrlWT=(unsigned short*)tk((size_t)4224*1024*2);
    B.p20WT=(unsigned short*)tk((size_t)3072*1024*2);
    B.outWT=(unsigned short*)tk((size_t)1024*2048*2);
    B.finals=(float2*)tk(NT*64);
    B.carry=(float2*)tk(NT*64);
    B.gbuf=(float*)tk(NT*16*4);
    B.bbuf=(float*)tk(NT*16*4);
    B.need=off;
    return B;
  };

  Bufs Bf = mk(8192);
  Bufs Bh = mk(4096);
  Bufs B; size_t NT; int nb;
  if      (Bf.need <= ws_size){ B=Bf; NT=8192; nb=2; }
  else if (Bh.need <= ws_size){ B=Bh; NT=4096; nb=1; }
  else {
    k_fill<<<2048,256,0,stream>>>(out, (float)((double)ws_size), (long)out_size);
    return;
  }

  // weight prep (once; regions never overlaid)
  k_transpose<<<dim3(132,32),256,0,stream>>>(ctrlW, B.ctrlWT, 1024, 4128, 4224);
  k_transpose<<<dim3(96,32), 256,0,stream>>>(p20cW, B.p20WT, 1024, 3072, 3072);
  k_transpose<<<dim3(32,64), 256,0,stream>>>(outW,  B.outWT, 2048, 1024, 1024);

  for (int b0=0; b0<2; b0+=nb){
    const float* hidb = hidden + (size_t)b0*SEQ*1024;
    float* outp = out + (size_t)b0*SEQ*1024;
    // P20 scan step 1 + fused hidden f32->bf16 conversion
    k_scan1<<<nb*128,256,0,stream>>>(hidb,dlog,theta,B.finals,B.E_hid);
    // ctrl projection with fused g/beta/gate epilogue (consumes E_hid)
    k_gemm_ctrl<<<dim3(33,NT/128),256,0,stream>>>(B.E_hid,1024, B.ctrlWT,1024,
                                                  B.ctrl, B.gbuf, B.bbuf, B.gateb, ctrlb);
    // P20 scan steps 2-3 (scan3 overwrites E region AFTER ctrl-GEMM consumed it)
    k_scan2<<<nb*2, 256,0,stream>>>(dlog,theta,B.finals,B.carry,nb);
    k_scan3<<<nb*128,256,0,stream>>>(hidb,dlog,theta,B.carry,B.E_p20);
    k_rms_p20<<<(int)NT,256,0,stream>>>(B.E_p20,vns,B.fused);
    // causal conv + silu (raw)
    k_conv<<<dim3(12,NT/16),256,0,stream>>>(B.ctrl,qw,kw,vw,B.Qb,B.Kb,B.Vb);
    // p20 qkv projection + ramp mix + l2norm (in-place into Q/K/V)
    k_gemm_qkv<<<dim3(24,NT/128),256,0,stream>>>(B.fused+1024,2048, B.p20WT,1024,
                                                 ramp, B.Qb,B.Kb,B.Vb);
    // gated delta rule (chunkwise WY)
    k_phase1<<<(int)(NT/4),64,0,stream>>>(B.Kb,B.Vb,B.gbuf,B.bbuf,B.uvT,B.Wrm,B.Mc,B.BcT);
    k_phase2<<<nb*64,64,0,stream>>>(B.Mc,B.BcT,B.Sst);
    k_phase3<<<(int)(NT/4),64,0,stream>>>(B.Qb,B.Kb,B.gbuf,B.uvT,B.Wrm,B.Sst,mns,B.fused);
    // out = sigmoid(gate) * (fused @ out_W + b)
    k_gemm<<<dim3(8,NT/128),256,0,stream>>>(B.fused,2048, B.outWT,2048,
                                            nullptr,outp,1024, 2048,1024, outb, B.gateb,1024);
  }
}